// Round 3
// baseline (3746.277 us; speedup 1.0000x reference)
//
#include <hip/hip_runtime.h>
#include <stdint.h>

typedef unsigned long long u64;
typedef unsigned int u32;
typedef unsigned char u8;

// ---------------------------------------------------------------------------
// EdgePool GNN pipeline.  N=100000, E=800000, F=128, H=64, G=8, C=10. f32.
// R1: two-stage k_gmp (was 4x1270us of same-address global atomics).
// R2: (a) dst-CSR + k_gather replaces k_aggregate's 51M scattered atomics
//     (289 Gatomic/s L2 ceiling, 177us x4); (b) persistent k_match with
//     software device barrier replaces 64 round-launches + serial tail;
//     (c) k_raw factored into per-node dots (409MB -> 38MB reads);
//     (d) conv3/4 guarded by nclus (skip ~45% dead rows).
// ---------------------------------------------------------------------------

static __device__ __forceinline__ u32 enc_f32(float f) {
  u32 u = __float_as_uint(f);
  return (u & 0x80000000u) ? ~u : (u | 0x80000000u);
}
static __device__ __forceinline__ float dec_f32(u32 u) {
  u32 b = (u & 0x80000000u) ? (u & 0x7fffffffu) : ~u;
  return __uint_as_float(b);
}

// out[n][64] = in[n][K] @ W[64][K]^T   (W staged in LDS, lane-uniform reads)
template <int K>
__global__ void k_transform(const float* __restrict__ x, const float* __restrict__ w,
                            const int* __restrict__ nvP, float* __restrict__ out, int n) {
  __shared__ float ws[64 * K];
  for (int i = threadIdx.x; i < 64 * K; i += blockDim.x) ws[i] = w[i];
  __syncthreads();
  int node = blockIdx.x * blockDim.x + threadIdx.x;
  if (node >= n) return;
  if (nvP && node >= *nvP) return;
  const float* xr = x + (size_t)node * K;
  float acc[64];
#pragma unroll
  for (int o = 0; o < 64; ++o) acc[o] = 0.f;
  for (int k = 0; k < K; k += 4) {
    float4 xv = *reinterpret_cast<const float4*>(xr + k);
#pragma unroll
    for (int o = 0; o < 64; ++o) {
      float4 wv = *reinterpret_cast<const float4*>(&ws[o * K + k]);
      acc[o] = fmaf(xv.x, wv.x, acc[o]);
      acc[o] = fmaf(xv.y, wv.y, acc[o]);
      acc[o] = fmaf(xv.z, wv.z, acc[o]);
      acc[o] = fmaf(xv.w, wv.w, acc[o]);
    }
  }
  float4* orow = reinterpret_cast<float4*>(out + (size_t)node * 64);
#pragma unroll
  for (int o = 0; o < 16; ++o)
    orow[o] = make_float4(acc[4 * o], acc[4 * o + 1], acc[4 * o + 2], acc[4 * o + 3]);
}

__global__ void k_count(const int* __restrict__ dst, int* __restrict__ cnt, int e) {
  int i = blockIdx.x * blockDim.x + threadIdx.x;
  if (i < e) atomicAdd(&cnt[dst[i]], 1);
}

// ---- 3-kernel exclusive scan over nc ints (nc ~ 100002) ----
__global__ void k_scan_sums(const int* __restrict__ in, int* __restrict__ bsum, int n) {
  __shared__ int sd[256];
  int base = blockIdx.x << 10;
  int s = 0;
  for (int j = threadIdx.x; j < 1024; j += 256) {
    int id = base + j;
    s += (id < n) ? in[id] : 0;
  }
  sd[threadIdx.x] = s;
  __syncthreads();
  for (int w = 128; w > 0; w >>= 1) {
    if (threadIdx.x < w) sd[threadIdx.x] += sd[threadIdx.x + w];
    __syncthreads();
  }
  if (threadIdx.x == 0) bsum[blockIdx.x] = sd[0];
}
__global__ void k_scan_tops(int* __restrict__ bsum, int nb) {
  if (threadIdx.x == 0 && blockIdx.x == 0) {
    int acc = 0;
    for (int i = 0; i < nb; ++i) { int v = bsum[i]; bsum[i] = acc; acc += v; }
  }
}
__global__ void k_scan_out(const int* __restrict__ in, const int* __restrict__ bsum,
                           int* __restrict__ rowptr, int* __restrict__ pos, int n) {
  __shared__ int sd[256];
  int base = blockIdx.x << 10;
  int i0 = base + threadIdx.x * 4;
  int v0 = 0, v1 = 0, v2 = 0, v3 = 0;
  if (i0 < n) v0 = in[i0];
  if (i0 + 1 < n) v1 = in[i0 + 1];
  if (i0 + 2 < n) v2 = in[i0 + 2];
  if (i0 + 3 < n) v3 = in[i0 + 3];
  sd[threadIdx.x] = v0 + v1 + v2 + v3;
  __syncthreads();
  for (int off = 1; off < 256; off <<= 1) {
    int add = (threadIdx.x >= off) ? sd[threadIdx.x - off] : 0;
    __syncthreads();
    sd[threadIdx.x] += add;
    __syncthreads();
  }
  int excl = bsum[blockIdx.x] + (threadIdx.x ? sd[threadIdx.x - 1] : 0);
  if (i0 < n) { rowptr[i0] = excl; pos[i0] = excl; }
  excl += v0;
  if (i0 + 1 < n) { rowptr[i0 + 1] = excl; pos[i0 + 1] = excl; }
  excl += v1;
  if (i0 + 2 < n) { rowptr[i0 + 2] = excl; pos[i0 + 2] = excl; }
  excl += v2;
  if (i0 + 3 < n) { rowptr[i0 + 3] = excl; pos[i0 + 3] = excl; }
}

__global__ void k_fill(const int* __restrict__ src, const int* __restrict__ dst,
                       int* __restrict__ pos, int* __restrict__ col, int e, int n) {
  int i = blockIdx.x * blockDim.x + threadIdx.x;
  if (i >= e) return;
  int d = dst[i];
  if (d >= n) return;  // sentinel (pooled duplicates)
  int j = atomicAdd(&pos[d], 1);
  col[j] = src[i];
}

// CSR gather: wave per dst node, lane = feature; coalesced 256B row loads.
__global__ void k_gather(const float* __restrict__ r, const int* __restrict__ rowptr,
                         const int* __restrict__ col, const int* __restrict__ nvP,
                         float* __restrict__ agg, int n) {
  int wv = (blockIdx.x * blockDim.x + threadIdx.x) >> 6;
  int lane = threadIdx.x & 63;
  if (wv >= n) return;
  if (nvP && wv >= *nvP) return;
  int b = rowptr[wv], e2 = rowptr[wv + 1];
  float s = 0.f;
  for (int j = b; j < e2; ++j) s += r[(size_t)col[j] * 64 + lane];
  agg[(size_t)wv * 64 + lane] = s;
}

// h = relu(agg/deg + b + xin @ w_root^T)   deg from rowptr
template <int K>
__global__ void k_finish(const float* __restrict__ xin, const float* __restrict__ agg,
                         const int* __restrict__ rowptr, const float* __restrict__ w_root,
                         const float* __restrict__ bias, const int* __restrict__ nvP,
                         float* __restrict__ hout, int n) {
  __shared__ float ws[64 * K];
  for (int i = threadIdx.x; i < 64 * K; i += blockDim.x) ws[i] = w_root[i];
  __syncthreads();
  int node = blockIdx.x * blockDim.x + threadIdx.x;
  if (node >= n) return;
  if (nvP && node >= *nvP) return;
  const float* xr = xin + (size_t)node * K;
  float acc[64];
#pragma unroll
  for (int o = 0; o < 64; ++o) acc[o] = bias[o];
  for (int k = 0; k < K; k += 4) {
    float4 xv = *reinterpret_cast<const float4*>(xr + k);
#pragma unroll
    for (int o = 0; o < 64; ++o) {
      float4 wv = *reinterpret_cast<const float4*>(&ws[o * K + k]);
      acc[o] = fmaf(xv.x, wv.x, acc[o]);
      acc[o] = fmaf(xv.y, wv.y, acc[o]);
      acc[o] = fmaf(xv.z, wv.z, acc[o]);
      acc[o] = fmaf(xv.w, wv.w, acc[o]);
    }
  }
  int deg = rowptr[node + 1] - rowptr[node];
  float inv = deg > 0 ? 1.f / (float)deg : 0.f;
  const float* ar = agg + (size_t)node * 64;
  float4* hr = reinterpret_cast<float4*>(hout + (size_t)node * 64);
#pragma unroll
  for (int o4 = 0; o4 < 16; ++o4) {
    float4 a = reinterpret_cast<const float4*>(ar)[o4];
    float4 v;
    v.x = fmaf(a.x, inv, acc[4 * o4 + 0]); v.x = v.x > 0.f ? v.x : 0.f;
    v.y = fmaf(a.y, inv, acc[4 * o4 + 1]); v.y = v.y > 0.f ? v.y : 0.f;
    v.z = fmaf(a.z, inv, acc[4 * o4 + 2]); v.z = v.z > 0.f ? v.z : 0.f;
    v.w = fmaf(a.w, inv, acc[4 * o4 + 3]); v.w = v.w > 0.f ? v.w : 0.f;
    hr[o4] = v;
  }
}

// global mean pool, two-stage (R1)
__global__ void k_gmp(const float* __restrict__ h, const int* __restrict__ batch,
                      const int* __restrict__ gP, float* __restrict__ xs_sum,
                      float* __restrict__ gcnt, int count_nodes, int n) {
  __shared__ float sacc[8 * 64];
  __shared__ float scnt[8];
  int G = *gP;
  for (int i = threadIdx.x; i < 8 * 64; i += blockDim.x) sacc[i] = 0.f;
  if (threadIdx.x < 8) scnt[threadIdx.x] = 0.f;
  __syncthreads();
  int lane = threadIdx.x & 63, w = threadIdx.x >> 6;
  int stride = gridDim.x * 4;
  for (int node = blockIdx.x * 4 + w; node < n; node += stride) {
    int g = batch[node];
    if (g < 0 || g >= G || g >= 8) continue;
    float v = h[(size_t)node * 64 + lane];
    atomicAdd(&sacc[g * 64 + lane], v);
    if (count_nodes && lane == 0) atomicAdd(&scnt[g], 1.f);
  }
  __syncthreads();
  int lim = (G < 8 ? G : 8) * 64;
  for (int i = threadIdx.x; i < lim; i += blockDim.x) {
    float s = sacc[i];
    if (s != 0.f) atomicAdd(&xs_sum[i], s);
  }
  if (count_nodes && threadIdx.x < 8) {
    float c = scnt[threadIdx.x];
    if (c != 0.f) atomicAdd(&gcnt[threadIdx.x], c);
  }
}

// per-node halves of the edge score: a = h.pw[0:64], b = h.pw[64:128]
__global__ void k_dots(const float* __restrict__ h, const float* __restrict__ pw,
                       float* __restrict__ aN, float* __restrict__ bN, int n) {
  int wv = (blockIdx.x * blockDim.x + threadIdx.x) >> 6;
  int lane = threadIdx.x & 63;
  if (wv >= n) return;
  float v = h[(size_t)wv * 64 + lane];
  float d1 = v * pw[lane];
  float d2 = v * pw[64 + lane];
#pragma unroll
  for (int off = 32; off > 0; off >>= 1) {
    d1 += __shfl_down(d1, off, 64);
    d2 += __shfl_down(d2, off, 64);
  }
  if (lane == 0) { aN[wv] = d1; bN[wv] = d2; }
}

__global__ void k_raw2(const float* __restrict__ aN, const float* __restrict__ bN,
                       const float* __restrict__ pbp, const int* __restrict__ src,
                       const int* __restrict__ dst, float* __restrict__ raw, int e) {
  int i = blockIdx.x * blockDim.x + threadIdx.x;
  if (i >= e) return;
  raw[i] = aN[src[i]] + bN[dst[i]] + pbp[0];
}

__global__ void k_max(const float* __restrict__ raw, const int* __restrict__ dst,
                      u32* __restrict__ m_enc, int e) {
  int i = blockIdx.x * blockDim.x + threadIdx.x;
  if (i < e) atomicMax(&m_enc[dst[i]], enc_f32(raw[i]));
}

__global__ void k_den(const float* __restrict__ raw, const int* __restrict__ dst,
                      const u32* __restrict__ m_enc, float* __restrict__ den, int e) {
  int i = blockIdx.x * blockDim.x + threadIdx.x;
  if (i >= e) return;
  int d = dst[i];
  atomicAdd(&den[d], expf(raw[i] - dec_f32(m_enc[d])));
}

// score (in place over raw) + sort key
__global__ void k_score(float* __restrict__ rawsc, const int* __restrict__ dst,
                        const u32* __restrict__ m_enc, const float* __restrict__ den,
                        u64* __restrict__ key, int e) {
  int i = blockIdx.x * blockDim.x + threadIdx.x;
  if (i >= e) return;
  int d = dst[i];
  float sc = expf(rawsc[i] - dec_f32(m_enc[d])) / den[d] + 0.5f;
  rawsc[i] = sc;
  key[i] = ((u64)(~__float_as_uint(sc)) << 32) | (u32)i;  // score desc, idx asc
}

// Persistent greedy matching: locally-dominant rounds, software device barrier.
// 512 blocks x 256 thr (<=128 VGPR -> >=1024-block residency capacity). Exact
// greedy over (score desc, idx asc); loops until alive-edge list is empty.
__global__ __launch_bounds__(256, 4) void k_match(
    const u64* __restrict__ key, const int* __restrict__ src, const int* __restrict__ dst,
    int* __restrict__ dead, u8* __restrict__ matched,
    u64* __restrict__ b0, u64* __restrict__ b1,
    int* __restrict__ listA, int* __restrict__ listB,
    int* __restrict__ cnts, u32* __restrict__ bar, int E) {
  const int T = gridDim.x * blockDim.x;
  const int gid = blockIdx.x * blockDim.x + threadIdx.x;
  u32 ph = 0;
  auto barrier = [&]() {
    __syncthreads();
    if (threadIdx.x == 0) {
      __threadfence();  // agent release: L2 writeback of prior plain stores
      __hip_atomic_fetch_add(bar, 1u, __ATOMIC_RELAXED, __HIP_MEMORY_SCOPE_AGENT);
      ++ph;
      u32 tgt = ph * gridDim.x;
      while (__hip_atomic_load(bar, __ATOMIC_RELAXED, __HIP_MEMORY_SCOPE_AGENT) < tgt)
        __builtin_amdgcn_s_sleep(2);
      __threadfence();  // agent acquire: invalidate L1/L2 for fresh plain loads
    } else {
      ++ph;
    }
    __syncthreads();
  };

  u64* bcur = b0;
  u64* bnext = b1;
  int n = E;
  for (int round = 0;; ++round) {
    int* outc = &cnts[round & 1];
    int* lout = (round & 1) ? listB : listA;
    const int* linp = (round & 1) ? listA : listB;
    // Phase A: filter dead, claim node minima, compact alive list
    for (int i = gid; i < n; i += T) {
      int e = (round == 0) ? i : linp[i];
      int s = src[e], d = dst[e];
      if (dead[s] || dead[d]) continue;
      u64 k = key[e];
      atomicMin(&bcur[s], k);
      if (d != s) atomicMin(&bcur[d], k);
      bnext[s] = ~0ull;
      bnext[d] = ~0ull;
      lout[atomicAdd(outc, 1)] = e;
    }
    barrier();
    int n2 = *outc;
    if (n2 == 0 || round > 100000) break;
    // Phase B: locally-dominant edges match
    for (int i = gid; i < n2; i += T) {
      int e = lout[i];
      int s = src[e], d = dst[e];
      u64 k = key[e];
      if (bcur[s] == k && (d == s || bcur[d] == k)) {
        matched[e] = 1;
        dead[s] = 1;
        dead[d] = 1;
      }
    }
    if (gid == 0) cnts[(round + 1) & 1] = 0;  // counter for round+1
    barrier();
    u64* t = bcur; bcur = bnext; bnext = t;
    n = n2;
  }
}

__global__ void k_clinit(int* __restrict__ new_batch, const int* __restrict__ gP, int n) {
  int i = blockIdx.x * blockDim.x + threadIdx.x;
  if (i < n) new_batch[i] = *gP;
}

__global__ void k_build_m(const u8* __restrict__ matched, const int* __restrict__ src,
                          const int* __restrict__ dst, const int* __restrict__ batch,
                          int* __restrict__ cluster, int* __restrict__ new_batch,
                          int* __restrict__ nclus, float* __restrict__ gccnt, int e) {
  __shared__ int sc[8];
  if (threadIdx.x < 8) sc[threadIdx.x] = 0;
  __syncthreads();
  int i = blockIdx.x * blockDim.x + threadIdx.x;
  if (i < e && matched[i]) {
    int c = atomicAdd(nclus, 1);
    int s = src[i], d = dst[i];
    cluster[s] = c;
    cluster[d] = c;
    int g = batch[s];
    new_batch[c] = g;
    if (g >= 0 && g < 8) atomicAdd(&sc[g], 1);
  }
  __syncthreads();
  if (threadIdx.x < 8 && sc[threadIdx.x] > 0)
    atomicAdd(&gccnt[threadIdx.x], (float)sc[threadIdx.x]);
}

__global__ void k_build_s(const int* __restrict__ dead, const int* __restrict__ batch,
                          int* __restrict__ cluster, int* __restrict__ new_batch,
                          int* __restrict__ nclus, float* __restrict__ gccnt, int n) {
  __shared__ int sc[8];
  if (threadIdx.x < 8) sc[threadIdx.x] = 0;
  __syncthreads();
  int i = blockIdx.x * blockDim.x + threadIdx.x;
  if (i < n && !dead[i]) {
    int c = atomicAdd(nclus, 1);
    cluster[i] = c;
    int g = batch[i];
    new_batch[c] = g;
    if (g >= 0 && g < 8) atomicAdd(&sc[g], 1);
  }
  __syncthreads();
  if (threadIdx.x < 8 && sc[threadIdx.x] > 0)
    atomicAdd(&gccnt[threadIdx.x], (float)sc[threadIdx.x]);
}

// new_x rows: matched pairs (scaled) + singletons; every cluster row written.
__global__ void k_newx(const u8* __restrict__ matched, const int* __restrict__ dead,
                       const int* __restrict__ src, const int* __restrict__ dst,
                       const int* __restrict__ cluster, const float* __restrict__ score,
                       const float* __restrict__ h2, float* __restrict__ new_x,
                       int e, int n) {
  int idx = blockIdx.x * blockDim.x + threadIdx.x;
  int item = idx >> 6, lane = idx & 63;
  if (item < e) {
    if (!matched[item]) return;
    int s = src[item], d = dst[item];
    int c = cluster[s];
    float v = h2[(size_t)s * 64 + lane];
    if (d != s) v += h2[(size_t)d * 64 + lane];
    new_x[(size_t)c * 64 + lane] = v * score[item];
  } else if (item < e + n) {
    int node = item - e;
    if (dead[node]) return;
    new_x[(size_t)cluster[node] * 64 + lane] = h2[(size_t)node * 64 + lane];
  }
}

#define HBITS 21
#define HMASK ((1u << HBITS) - 1u)

// coalesce(cluster[edge_index]): hash-dedup; dups -> sentinel n; counts kept.
__global__ void k_dedup(const int* __restrict__ src, const int* __restrict__ dst,
                        const int* __restrict__ cluster, u64* __restrict__ table,
                        int* __restrict__ ns, int* __restrict__ nd,
                        int* __restrict__ cnt, int e, int n) {
  int i = blockIdx.x * blockDim.x + threadIdx.x;
  if (i >= e) return;
  int cs_ = cluster[src[i]], cd_ = cluster[dst[i]];
  u64 kk = (u64)cs_ * (u64)(n + 1) + (u64)cd_;
  u32 pos = (u32)((kk * 0x9E3779B97F4A7C15ull) >> 43) & HMASK;
  while (true) {
    u64 old = atomicCAS(&table[pos], ~0ull, kk);
    if (old == ~0ull) {
      ns[i] = cs_; nd[i] = cd_;
      atomicAdd(&cnt[cd_], 1);
      return;
    }
    if (old == kk) { ns[i] = n; nd[i] = n; return; }
    pos = (pos + 1) & HMASK;
  }
}

// JK cat + lin1 + relu + lin2 + log_softmax. single block.
__global__ void k_head(const float* __restrict__ xs_sum /*4*8*64*/,
                       const float* __restrict__ gncnt, const float* __restrict__ gccnt,
                       const float* __restrict__ l1w, const float* __restrict__ l1b,
                       const float* __restrict__ l2w, const float* __restrict__ l2b,
                       const int* __restrict__ gP, float* __restrict__ out, int C) {
  __shared__ float z[8][256];
  __shared__ float z1[8][64];
  __shared__ float z2[8][16];
  int G = *gP;
  int tid = threadIdx.x;
  int p = tid >> 6, f = tid & 63;
  for (int g = 0; g < G; ++g) {
    float c = (p < 2) ? gncnt[g] : gccnt[g];
    if (c < 1.f) c = 1.f;
    z[g][tid] = xs_sum[(p * 8 + g) * 64 + f] / c;
  }
  __syncthreads();
  for (int idx = tid; idx < G * 64; idx += blockDim.x) {
    int g = idx >> 6, o = idx & 63;
    float a = l1b[o];
    for (int k = 0; k < 256; ++k) a = fmaf(z[g][k], l1w[o * 256 + k], a);
    z1[g][o] = a > 0.f ? a : 0.f;
  }
  __syncthreads();
  for (int idx = tid; idx < G * C; idx += blockDim.x) {
    int g = idx / C, c = idx % C;
    float a = l2b[c];
    for (int k = 0; k < 64; ++k) a = fmaf(z1[g][k], l2w[c * 64 + k], a);
    z2[g][c] = a;
  }
  __syncthreads();
  if (tid < G) {
    float m = z2[tid][0];
    for (int c = 1; c < C; ++c) m = fmaxf(m, z2[tid][c]);
    float s = 0.f;
    for (int c = 0; c < C; ++c) s += expf(z2[tid][c] - m);
    float lse = m + logf(s);
    for (int c = 0; c < C; ++c) out[tid * C + c] = z2[tid][c] - lse;
  }
}

extern "C" void kernel_launch(void* const* d_in, const int* in_sizes, int n_in,
                              void* d_out, int out_size, void* d_ws, size_t ws_size,
                              hipStream_t stream) {
  const float* x       = (const float*)d_in[0];
  const int*   ei      = (const int*)d_in[1];
  const int*   batch   = (const int*)d_in[2];
  const float* w_rel1  = (const float*)d_in[3];
  const float* b_rel1  = (const float*)d_in[4];
  const float* w_root1 = (const float*)d_in[5];
  const float* w_rel2  = (const float*)d_in[6];
  const float* b_rel2  = (const float*)d_in[7];
  const float* w_root2 = (const float*)d_in[8];
  const float* w_rel3  = (const float*)d_in[9];
  const float* b_rel3  = (const float*)d_in[10];
  const float* w_root3 = (const float*)d_in[11];
  const float* w_rel4  = (const float*)d_in[12];
  const float* b_rel4  = (const float*)d_in[13];
  const float* w_root4 = (const float*)d_in[14];
  const float* pool_w  = (const float*)d_in[15];
  const float* pool_b  = (const float*)d_in[16];
  const float* lin1_w  = (const float*)d_in[17];
  const float* lin1_b  = (const float*)d_in[18];
  const float* lin2_w  = (const float*)d_in[19];
  const float* lin2_b  = (const float*)d_in[20];
  const int*   gP      = (const int*)d_in[21];
  float* out = (float*)d_out;

  const int N = in_sizes[2];
  const int E = in_sizes[1] / 2;
  const int C = in_sizes[20];
  const int* src = ei;
  const int* dst = ei + E;

  // ---- workspace layout ----
  char* w = (char*)d_ws;
  auto alloc = [&](size_t bytes) -> char* {
    char* p = w;
    w += (bytes + 255) & ~(size_t)255;
    return p;
  };
  float* r      = (float*)alloc((size_t)N * 64 * 4);
  float* agg    = (float*)alloc((size_t)(N + 1) * 64 * 4);  // also hash region
  float* hA     = (float*)alloc((size_t)N * 64 * 4);        // h1 -> new_x -> h4
  float* hB     = (float*)alloc((size_t)N * 64 * 4);        // h2 -> h3
  float* score  = (float*)alloc((size_t)E * 4);             // raw -> score
  u64*   key    = (u64*)alloc((size_t)E * 8);               // first E ints alias: col
  int*   listA  = (int*)alloc((size_t)E * 4);               // aN -> list -> ns
  int*   listB  = (int*)alloc((size_t)E * 4);               // bN -> list -> nd
  u64*   best0  = (u64*)alloc((size_t)N * 8);
  u64*   best1  = (u64*)alloc((size_t)N * 8);
  int*   rowptr = (int*)alloc((size_t)(N + 2) * 4);
  int*   pos    = (int*)alloc((size_t)(N + 2) * 4);
  char* zstart = w;                                         // zeroed block
  int*   cnt       = (int*)alloc((size_t)(N + 2) * 4);
  int*   bsum      = (int*)alloc(1024);
  u32*   m_enc     = (u32*)alloc((size_t)N * 4);
  float* den       = (float*)alloc((size_t)N * 4);
  int*   dead      = (int*)alloc((size_t)N * 4);
  u8*    matched   = (u8*)alloc((size_t)E);
  int*   cluster   = (int*)alloc((size_t)N * 4);
  int*   new_batch = (int*)alloc((size_t)N * 4);
  float* small     = (float*)alloc(16384);
  size_t zbytes = (size_t)(w - zstart);
  if ((size_t)(w - (char*)d_ws) > ws_size) return;  // fail loudly

  int*   col = (int*)key;          // alias: col dead before key written / after key dead
  float* aN  = (float*)listA;      // alias: dots dead before lists used
  float* bN  = (float*)listB;

  float* xs_sum = small;                 // [4][8][64]
  float* gncnt  = small + 2048;          // [8]
  float* gccnt  = small + 2056;          // [8]
  int*   cptr   = (int*)(small + 2064);  // c0, c1
  int*   nclusP = (int*)(small + 2066);
  u32*   barP   = (u32*)(small + 2068);

  const int TB = 256;
  const int gN = (N + TB - 1) / TB;
  const int gE = (E + TB - 1) / TB;
  const int gNw = (int)(((size_t)N * 64 + TB - 1) / TB);       // wave per node
  const int gENw = (int)(((size_t)(E + N) * 64 + TB - 1) / TB);
  const int nc = N + 2;                  // scan length (trailing zero -> total)
  const int nb = (nc + 1023) / 1024;

  hipMemsetAsync(zstart, 0, zbytes, stream);
  hipMemsetAsync(best0, 0xFF, (size_t)N * 8, stream);
  hipMemsetAsync(best1, 0xFF, (size_t)N * 8, stream);

  // ---- CSR for original edges ----
  k_count<<<gE, TB, 0, stream>>>(dst, cnt, E);
  k_scan_sums<<<nb, TB, 0, stream>>>(cnt, bsum, nc);
  k_scan_tops<<<1, 64, 0, stream>>>(bsum, nb);
  k_scan_out<<<nb, TB, 0, stream>>>(cnt, bsum, rowptr, pos, nc);
  k_fill<<<gE, TB, 0, stream>>>(src, dst, pos, col, E, N);

  // ---- conv1 (F=128 -> 64) + gmp xs0 ----
  k_transform<128><<<gN, TB, 0, stream>>>(x, w_rel1, nullptr, r, N);
  k_gather<<<gNw, TB, 0, stream>>>(r, rowptr, col, nullptr, agg, N);
  k_finish<128><<<gN, TB, 0, stream>>>(x, agg, rowptr, w_root1, b_rel1, nullptr, hA, N);
  k_gmp<<<1024, TB, 0, stream>>>(hA, batch, gP, xs_sum + 0 * 512, gncnt, 1, N);

  // ---- conv2 (64 -> 64) + gmp xs1 ----
  k_transform<64><<<gN, TB, 0, stream>>>(hA, w_rel2, nullptr, r, N);
  k_gather<<<gNw, TB, 0, stream>>>(r, rowptr, col, nullptr, agg, N);
  k_finish<64><<<gN, TB, 0, stream>>>(hA, agg, rowptr, w_root2, b_rel2, nullptr, hB, N);
  k_gmp<<<1024, TB, 0, stream>>>(hB, batch, gP, xs_sum + 1 * 512, nullptr, 0, N);

  // ---- edge pooling: scores ----
  k_dots<<<gNw, TB, 0, stream>>>(hB, pool_w, aN, bN, N);
  k_raw2<<<gE, TB, 0, stream>>>(aN, bN, pool_b, src, dst, score, E);
  k_max<<<gE, TB, 0, stream>>>(score, dst, m_enc, E);
  k_den<<<gE, TB, 0, stream>>>(score, dst, m_enc, den, E);
  k_score<<<gE, TB, 0, stream>>>(score, dst, m_enc, den, key, E);

  // ---- greedy matching (persistent, exact) ----
  k_match<<<512, TB, 0, stream>>>(key, src, dst, dead, matched, best0, best1,
                                  listA, listB, cptr, barP, E);

  // ---- clusters, new_x, new_batch ----
  k_clinit<<<gN, TB, 0, stream>>>(new_batch, gP, N);
  k_build_m<<<gE, TB, 0, stream>>>(matched, src, dst, batch, cluster, new_batch, nclusP, gccnt, E);
  k_build_s<<<gN, TB, 0, stream>>>(dead, batch, cluster, new_batch, nclusP, gccnt, N);
  k_newx<<<gENw, TB, 0, stream>>>(matched, dead, src, dst, cluster, score, hB, hA, E, N);

  // ---- coalesce edges + CSR for pooled edges ----
  hipMemsetAsync(agg, 0xFF, ((size_t)1 << HBITS) * 8, stream);
  hipMemsetAsync(cnt, 0, (size_t)nc * 4, stream);
  k_dedup<<<gE, TB, 0, stream>>>(src, dst, cluster, (u64*)agg, listA, listB, cnt, E, N);
  k_scan_sums<<<nb, TB, 0, stream>>>(cnt, bsum, nc);
  k_scan_tops<<<1, 64, 0, stream>>>(bsum, nb);
  k_scan_out<<<nb, TB, 0, stream>>>(cnt, bsum, rowptr, pos, nc);
  k_fill<<<gE, TB, 0, stream>>>(listA, listB, pos, col, E, N);

  // ---- conv3 (64 -> 64) + gmp xs2 ----
  k_transform<64><<<gN, TB, 0, stream>>>(hA, w_rel3, nclusP, r, N);
  k_gather<<<gNw, TB, 0, stream>>>(r, rowptr, col, nclusP, agg, N);
  k_finish<64><<<gN, TB, 0, stream>>>(hA, agg, rowptr, w_root3, b_rel3, nclusP, hB, N);
  k_gmp<<<1024, TB, 0, stream>>>(hB, new_batch, gP, xs_sum + 2 * 512, nullptr, 0, N);

  // ---- conv4 (64 -> 64) + gmp xs3 ----
  k_transform<64><<<gN, TB, 0, stream>>>(hB, w_rel4, nclusP, r, N);
  k_gather<<<gNw, TB, 0, stream>>>(r, rowptr, col, nclusP, agg, N);
  k_finish<64><<<gN, TB, 0, stream>>>(hB, agg, rowptr, w_root4, b_rel4, nclusP, hA, N);
  k_gmp<<<1024, TB, 0, stream>>>(hA, new_batch, gP, xs_sum + 3 * 512, nullptr, 0, N);

  // ---- head ----
  k_head<<<1, TB, 0, stream>>>(xs_sum, gncnt, gccnt, lin1_w, lin1_b, lin2_w, lin2_b, gP, out, C);
}

// Round 4
// 3303.696 us; speedup vs baseline: 1.1340x; 1.1340x over previous
//
#include <hip/hip_runtime.h>
#include <stdint.h>

typedef unsigned long long u64;
typedef unsigned int u32;
typedef unsigned char u8;

// ---------------------------------------------------------------------------
// EdgePool GNN pipeline.  N=100000, E=800000, F=128, H=64, G=8, C=10. f32.
// R1: two-stage k_gmp (was 4x1270us same-address global atomics).
// R2: dst-CSR gather (was 51M scattered atomics, 177us x4); factored raw
//     scores; nclus guards.
// R3: persistent-grid k_match regressed (2098us: __threadfence barrier =
//     full L2 writeback per block per round). Replaced by per-graph
//     single-workgroup matching (graphs are independent; __syncthreads only,
//     dead[] in LDS, bcur via L2 atomics). Also: k_dots fused into conv2
//     finish; k_newx cluster-driven; edge partition kernels added.
// ---------------------------------------------------------------------------

static __device__ __forceinline__ u32 enc_f32(float f) {
  u32 u = __float_as_uint(f);
  return (u & 0x80000000u) ? ~u : (u | 0x80000000u);
}
static __device__ __forceinline__ float dec_f32(u32 u) {
  u32 b = (u & 0x80000000u) ? (u & 0x7fffffffu) : ~u;
  return __uint_as_float(b);
}

// out[n][64] = in[n][K] @ W[64][K]^T   (W staged in LDS, lane-uniform reads)
template <int K>
__global__ void k_transform(const float* __restrict__ x, const float* __restrict__ w,
                            const int* __restrict__ nvP, float* __restrict__ out, int n) {
  __shared__ float ws[64 * K];
  for (int i = threadIdx.x; i < 64 * K; i += blockDim.x) ws[i] = w[i];
  __syncthreads();
  int node = blockIdx.x * blockDim.x + threadIdx.x;
  if (node >= n) return;
  if (nvP && node >= *nvP) return;
  const float* xr = x + (size_t)node * K;
  float acc[64];
#pragma unroll
  for (int o = 0; o < 64; ++o) acc[o] = 0.f;
  for (int k = 0; k < K; k += 4) {
    float4 xv = *reinterpret_cast<const float4*>(xr + k);
#pragma unroll
    for (int o = 0; o < 64; ++o) {
      float4 wv = *reinterpret_cast<const float4*>(&ws[o * K + k]);
      acc[o] = fmaf(xv.x, wv.x, acc[o]);
      acc[o] = fmaf(xv.y, wv.y, acc[o]);
      acc[o] = fmaf(xv.z, wv.z, acc[o]);
      acc[o] = fmaf(xv.w, wv.w, acc[o]);
    }
  }
  float4* orow = reinterpret_cast<float4*>(out + (size_t)node * 64);
#pragma unroll
  for (int o = 0; o < 16; ++o)
    orow[o] = make_float4(acc[4 * o], acc[4 * o + 1], acc[4 * o + 2], acc[4 * o + 3]);
}

__global__ void k_count(const int* __restrict__ dst, int* __restrict__ cnt, int e) {
  int i = blockIdx.x * blockDim.x + threadIdx.x;
  if (i < e) atomicAdd(&cnt[dst[i]], 1);
}

// ---- 3-kernel exclusive scan over nc ints ----
__global__ void k_scan_sums(const int* __restrict__ in, int* __restrict__ bsum, int n) {
  __shared__ int sd[256];
  int base = blockIdx.x << 10;
  int s = 0;
  for (int j = threadIdx.x; j < 1024; j += 256) {
    int id = base + j;
    s += (id < n) ? in[id] : 0;
  }
  sd[threadIdx.x] = s;
  __syncthreads();
  for (int w = 128; w > 0; w >>= 1) {
    if (threadIdx.x < w) sd[threadIdx.x] += sd[threadIdx.x + w];
    __syncthreads();
  }
  if (threadIdx.x == 0) bsum[blockIdx.x] = sd[0];
}
__global__ void k_scan_tops(int* __restrict__ bsum, int nb) {
  if (threadIdx.x == 0 && blockIdx.x == 0) {
    int acc = 0;
    for (int i = 0; i < nb; ++i) { int v = bsum[i]; bsum[i] = acc; acc += v; }
  }
}
__global__ void k_scan_out(const int* __restrict__ in, const int* __restrict__ bsum,
                           int* __restrict__ rowptr, int* __restrict__ pos, int n) {
  __shared__ int sd[256];
  int base = blockIdx.x << 10;
  int i0 = base + threadIdx.x * 4;
  int v0 = 0, v1 = 0, v2 = 0, v3 = 0;
  if (i0 < n) v0 = in[i0];
  if (i0 + 1 < n) v1 = in[i0 + 1];
  if (i0 + 2 < n) v2 = in[i0 + 2];
  if (i0 + 3 < n) v3 = in[i0 + 3];
  sd[threadIdx.x] = v0 + v1 + v2 + v3;
  __syncthreads();
  for (int off = 1; off < 256; off <<= 1) {
    int add = (threadIdx.x >= off) ? sd[threadIdx.x - off] : 0;
    __syncthreads();
    sd[threadIdx.x] += add;
    __syncthreads();
  }
  int excl = bsum[blockIdx.x] + (threadIdx.x ? sd[threadIdx.x - 1] : 0);
  if (i0 < n) { rowptr[i0] = excl; pos[i0] = excl; }
  excl += v0;
  if (i0 + 1 < n) { rowptr[i0 + 1] = excl; pos[i0 + 1] = excl; }
  excl += v1;
  if (i0 + 2 < n) { rowptr[i0 + 2] = excl; pos[i0 + 2] = excl; }
  excl += v2;
  if (i0 + 3 < n) { rowptr[i0 + 3] = excl; pos[i0 + 3] = excl; }
}

__global__ void k_fill(const int* __restrict__ src, const int* __restrict__ dst,
                       int* __restrict__ pos, int* __restrict__ col, int e, int n) {
  int i = blockIdx.x * blockDim.x + threadIdx.x;
  if (i >= e) return;
  int d = dst[i];
  if (d >= n) return;  // sentinel (pooled duplicates)
  int j = atomicAdd(&pos[d], 1);
  col[j] = src[i];
}

// CSR gather: wave per dst node, lane = feature; coalesced 256B row loads.
__global__ void k_gather(const float* __restrict__ r, const int* __restrict__ rowptr,
                         const int* __restrict__ col, const int* __restrict__ nvP,
                         float* __restrict__ agg, int n) {
  int wv = (blockIdx.x * blockDim.x + threadIdx.x) >> 6;
  int lane = threadIdx.x & 63;
  if (wv >= n) return;
  if (nvP && wv >= *nvP) return;
  int b = rowptr[wv], e2 = rowptr[wv + 1];
  float s = 0.f;
  for (int j = b; j < e2; ++j) s += r[(size_t)col[j] * 64 + lane];
  agg[(size_t)wv * 64 + lane] = s;
}

// h = relu(agg/deg + b + xin @ w_root^T); optional fused score-dot halves.
template <int K>
__global__ void k_finish(const float* __restrict__ xin, const float* __restrict__ agg,
                         const int* __restrict__ rowptr, const float* __restrict__ w_root,
                         const float* __restrict__ bias, const int* __restrict__ nvP,
                         float* __restrict__ hout, const float* __restrict__ pw,
                         float* __restrict__ aN, float* __restrict__ bN, int n) {
  __shared__ float ws[64 * K];
  __shared__ float pws[128];
  for (int i = threadIdx.x; i < 64 * K; i += blockDim.x) ws[i] = w_root[i];
  if (pw) for (int i = threadIdx.x; i < 128; i += blockDim.x) pws[i] = pw[i];
  __syncthreads();
  int node = blockIdx.x * blockDim.x + threadIdx.x;
  if (node >= n) return;
  if (nvP && node >= *nvP) return;
  const float* xr = xin + (size_t)node * K;
  float acc[64];
#pragma unroll
  for (int o = 0; o < 64; ++o) acc[o] = bias[o];
  for (int k = 0; k < K; k += 4) {
    float4 xv = *reinterpret_cast<const float4*>(xr + k);
#pragma unroll
    for (int o = 0; o < 64; ++o) {
      float4 wv = *reinterpret_cast<const float4*>(&ws[o * K + k]);
      acc[o] = fmaf(xv.x, wv.x, acc[o]);
      acc[o] = fmaf(xv.y, wv.y, acc[o]);
      acc[o] = fmaf(xv.z, wv.z, acc[o]);
      acc[o] = fmaf(xv.w, wv.w, acc[o]);
    }
  }
  int deg = rowptr[node + 1] - rowptr[node];
  float inv = deg > 0 ? 1.f / (float)deg : 0.f;
  const float* ar = agg + (size_t)node * 64;
  float4* hr = reinterpret_cast<float4*>(hout + (size_t)node * 64);
  float d1 = 0.f, d2 = 0.f;
#pragma unroll
  for (int o4 = 0; o4 < 16; ++o4) {
    float4 a = reinterpret_cast<const float4*>(ar)[o4];
    float4 v;
    v.x = fmaf(a.x, inv, acc[4 * o4 + 0]); v.x = v.x > 0.f ? v.x : 0.f;
    v.y = fmaf(a.y, inv, acc[4 * o4 + 1]); v.y = v.y > 0.f ? v.y : 0.f;
    v.z = fmaf(a.z, inv, acc[4 * o4 + 2]); v.z = v.z > 0.f ? v.z : 0.f;
    v.w = fmaf(a.w, inv, acc[4 * o4 + 3]); v.w = v.w > 0.f ? v.w : 0.f;
    hr[o4] = v;
    if (pw) {
      d1 = fmaf(v.x, pws[4 * o4 + 0], d1); d2 = fmaf(v.x, pws[64 + 4 * o4 + 0], d2);
      d1 = fmaf(v.y, pws[4 * o4 + 1], d1); d2 = fmaf(v.y, pws[64 + 4 * o4 + 1], d2);
      d1 = fmaf(v.z, pws[4 * o4 + 2], d1); d2 = fmaf(v.z, pws[64 + 4 * o4 + 2], d2);
      d1 = fmaf(v.w, pws[4 * o4 + 3], d1); d2 = fmaf(v.w, pws[64 + 4 * o4 + 3], d2);
    }
  }
  if (pw) { aN[node] = d1; bN[node] = d2; }
}

// global mean pool, two-stage (R1)
__global__ void k_gmp(const float* __restrict__ h, const int* __restrict__ batch,
                      const int* __restrict__ gP, float* __restrict__ xs_sum,
                      float* __restrict__ gcnt, int count_nodes, int n) {
  __shared__ float sacc[8 * 64];
  __shared__ float scnt[8];
  int G = *gP;
  for (int i = threadIdx.x; i < 8 * 64; i += blockDim.x) sacc[i] = 0.f;
  if (threadIdx.x < 8) scnt[threadIdx.x] = 0.f;
  __syncthreads();
  int lane = threadIdx.x & 63, w = threadIdx.x >> 6;
  int stride = gridDim.x * 4;
  for (int node = blockIdx.x * 4 + w; node < n; node += stride) {
    int g = batch[node];
    if (g < 0 || g >= G || g >= 8) continue;
    float v = h[(size_t)node * 64 + lane];
    atomicAdd(&sacc[g * 64 + lane], v);
    if (count_nodes && lane == 0) atomicAdd(&scnt[g], 1.f);
  }
  __syncthreads();
  int lim = (G < 8 ? G : 8) * 64;
  for (int i = threadIdx.x; i < lim; i += blockDim.x) {
    float s = sacc[i];
    if (s != 0.f) atomicAdd(&xs_sum[i], s);
  }
  if (count_nodes && threadIdx.x < 8) {
    float c = scnt[threadIdx.x];
    if (c != 0.f) atomicAdd(&gcnt[threadIdx.x], c);
  }
}

__global__ void k_raw2(const float* __restrict__ aN, const float* __restrict__ bN,
                       const float* __restrict__ pbp, const int* __restrict__ src,
                       const int* __restrict__ dst, float* __restrict__ raw, int e) {
  int i = blockIdx.x * blockDim.x + threadIdx.x;
  if (i >= e) return;
  raw[i] = aN[src[i]] + bN[dst[i]] + pbp[0];
}

__global__ void k_max(const float* __restrict__ raw, const int* __restrict__ dst,
                      u32* __restrict__ m_enc, int e) {
  int i = blockIdx.x * blockDim.x + threadIdx.x;
  if (i < e) atomicMax(&m_enc[dst[i]], enc_f32(raw[i]));
}

__global__ void k_den(const float* __restrict__ raw, const int* __restrict__ dst,
                      const u32* __restrict__ m_enc, float* __restrict__ den, int e) {
  int i = blockIdx.x * blockDim.x + threadIdx.x;
  if (i >= e) return;
  int d = dst[i];
  atomicAdd(&den[d], expf(raw[i] - dec_f32(m_enc[d])));
}

// score (in place over raw) + sort key
__global__ void k_score(float* __restrict__ rawsc, const int* __restrict__ dst,
                        const u32* __restrict__ m_enc, const float* __restrict__ den,
                        u64* __restrict__ key, int e) {
  int i = blockIdx.x * blockDim.x + threadIdx.x;
  if (i >= e) return;
  int d = dst[i];
  float sc = expf(rawsc[i] - dec_f32(m_enc[d])) / den[d] + 0.5f;
  rawsc[i] = sc;
  key[i] = ((u64)(~__float_as_uint(sc)) << 32) | (u32)i;  // score desc, idx asc
}

// ---- per-graph edge partition (block-aggregated counters) ----
__global__ void k_gcount(const int* __restrict__ src, const int* __restrict__ batch,
                         int* __restrict__ gec, int e) {
  __shared__ int sc[8];
  if (threadIdx.x < 8) sc[threadIdx.x] = 0;
  __syncthreads();
  int i = blockIdx.x * blockDim.x + threadIdx.x;
  if (i < e) {
    int g = batch[src[i]];
    if ((unsigned)g < 8u) atomicAdd(&sc[g], 1);
  }
  __syncthreads();
  if (threadIdx.x < 8 && sc[threadIdx.x]) atomicAdd(&gec[threadIdx.x], sc[threadIdx.x]);
}
__global__ void k_gscan(const int* __restrict__ gec, int* __restrict__ gbase,
                        int* __restrict__ gpos) {
  if (threadIdx.x == 0 && blockIdx.x == 0) {
    int acc = 0;
    for (int g = 0; g < 8; ++g) { gbase[g] = acc; gpos[g] = acc; acc += gec[g]; }
    gbase[8] = acc;
  }
}
// 1024-thread blocks: LDS rank + one global base-grab per g per block.
__global__ __launch_bounds__(1024) void k_gfill(
    const int* __restrict__ src, const int* __restrict__ dst,
    const int* __restrict__ batch, const u64* __restrict__ key,
    const int* __restrict__ gP, int* __restrict__ gpos,
    u64* __restrict__ egKey, int2* __restrict__ egSD, int e, int N) {
  __shared__ int scnt[8], sbase[8];
  if (threadIdx.x < 8) scnt[threadIdx.x] = 0;
  __syncthreads();
  int i = blockIdx.x * 1024 + threadIdx.x;
  int g = -1, rank = 0, s = 0, d = 0;
  if (i < e) {
    s = src[i]; d = dst[i];
    g = batch[s];
    if ((unsigned)g < 8u) rank = atomicAdd(&scnt[g], 1);
    else g = -1;
  }
  __syncthreads();
  if (threadIdx.x < 8 && scnt[threadIdx.x])
    sbase[threadIdx.x] = atomicAdd(&gpos[threadIdx.x], scnt[threadIdx.x]);
  __syncthreads();
  if (g < 0) return;
  int per = N / *gP;
  int base = g * per;
  int j = sbase[g] + rank;
  egKey[j] = key[i];
  egSD[j] = make_int2(s - base, d - base);
}

// Per-graph exact greedy matching: one 1024-thread workgroup per graph.
// dead[] in LDS; bcur/bnext via L2 atomics (agent-scope loads bypass L1);
// alive lists in global (sc0 load/store). __syncthreads between phases —
// no device-scope fences (R3 lesson: __threadfence = L2 writeback, ~2ms).
__global__ __launch_bounds__(1024) void k_match_wg(
    const u64* __restrict__ egKey, const int2* __restrict__ egSD,
    const int* __restrict__ gbase, const int* __restrict__ gP,
    u64* __restrict__ b0, u64* __restrict__ b1,
    int* __restrict__ listA, int* __restrict__ listB,
    int* __restrict__ dead, u8* __restrict__ matched, int N) {
  __shared__ u8 dead_s[16384];
  __shared__ int lcnt;
  int G = *gP;
  int g = blockIdx.x;
  if (g >= G) return;
  int per = N / G;
  if (per > 16384) per = 16384;
  int base = g * per;
  int re = gbase[g];
  int nE = gbase[g + 1] - re;
  int tid = threadIdx.x;
  for (int i = tid; i < per; i += 1024) dead_s[i] = 0;
  if (tid == 0) lcnt = 0;
  __syncthreads();
  u64* bcur = b0 + base;
  u64* bnext = b1 + base;
  int* lin = listA + re;
  int* lout = listB + re;
  int n = nE;
  for (int round = 0; n > 0 && round < 10000; ++round) {
    // Phase A: filter dead, claim node minima, reset next-buffer, compact
    for (int i = tid; i < n; i += 1024) {
      int rec = (round == 0)
                    ? (re + i)
                    : __hip_atomic_load(&lin[i], __ATOMIC_RELAXED, __HIP_MEMORY_SCOPE_AGENT);
      int2 sd = egSD[rec];
      if (dead_s[sd.x] | dead_s[sd.y]) continue;
      u64 k = egKey[rec];
      atomicMin(&bcur[sd.x], k);
      if (sd.y != sd.x) atomicMin(&bcur[sd.y], k);
      bnext[sd.x] = ~0ull;
      bnext[sd.y] = ~0ull;
      int j = atomicAdd(&lcnt, 1);
      __hip_atomic_store(&lout[j], rec, __ATOMIC_RELAXED, __HIP_MEMORY_SCOPE_AGENT);
    }
    __syncthreads();
    int n2 = lcnt;
    if (n2 == 0) break;
    // Phase B: locally-dominant edges match
    for (int i = tid; i < n2; i += 1024) {
      int rec = __hip_atomic_load(&lout[i], __ATOMIC_RELAXED, __HIP_MEMORY_SCOPE_AGENT);
      int2 sd = egSD[rec];
      u64 k = egKey[rec];
      u64 vs = __hip_atomic_load(&bcur[sd.x], __ATOMIC_RELAXED, __HIP_MEMORY_SCOPE_AGENT);
      if (vs == k &&
          (sd.y == sd.x ||
           __hip_atomic_load(&bcur[sd.y], __ATOMIC_RELAXED, __HIP_MEMORY_SCOPE_AGENT) == k)) {
        matched[(u32)k] = 1;
        dead_s[sd.x] = 1;
        dead_s[sd.y] = 1;
      }
    }
    if (tid == 0) lcnt = 0;
    __syncthreads();
    u64* tb = bcur; bcur = bnext; bnext = tb;
    int* tl = lin; lin = lout; lout = tl;
    n = n2;
  }
  __syncthreads();
  for (int i = tid; i < per; i += 1024) dead[base + i] = dead_s[i];
}

__global__ void k_clinit(int* __restrict__ new_batch, const int* __restrict__ gP, int n) {
  int i = blockIdx.x * blockDim.x + threadIdx.x;
  if (i < n) new_batch[i] = *gP;
}

__global__ void k_build_m(const u8* __restrict__ matched, const int* __restrict__ src,
                          const int* __restrict__ dst, const int* __restrict__ batch,
                          int* __restrict__ cluster, int* __restrict__ new_batch,
                          int* __restrict__ srcE, int* __restrict__ nclus,
                          float* __restrict__ gccnt, int e) {
  __shared__ int sc[8];
  if (threadIdx.x < 8) sc[threadIdx.x] = 0;
  __syncthreads();
  int i = blockIdx.x * blockDim.x + threadIdx.x;
  if (i < e && matched[i]) {
    int c = atomicAdd(nclus, 1);
    int s = src[i], d = dst[i];
    cluster[s] = c;
    cluster[d] = c;
    srcE[c] = i;
    int g = batch[s];
    new_batch[c] = g;
    if (g >= 0 && g < 8) atomicAdd(&sc[g], 1);
  }
  __syncthreads();
  if (threadIdx.x < 8 && sc[threadIdx.x] > 0)
    atomicAdd(&gccnt[threadIdx.x], (float)sc[threadIdx.x]);
}

__global__ void k_build_s(const int* __restrict__ dead, const int* __restrict__ batch,
                          int* __restrict__ cluster, int* __restrict__ new_batch,
                          int* __restrict__ srcE, int* __restrict__ nclus,
                          float* __restrict__ gccnt, int n) {
  __shared__ int sc[8];
  if (threadIdx.x < 8) sc[threadIdx.x] = 0;
  __syncthreads();
  int i = blockIdx.x * blockDim.x + threadIdx.x;
  if (i < n && !dead[i]) {
    int c = atomicAdd(nclus, 1);
    cluster[i] = c;
    srcE[c] = ~i;  // singleton: encoded node
    int g = batch[i];
    new_batch[c] = g;
    if (g >= 0 && g < 8) atomicAdd(&sc[g], 1);
  }
  __syncthreads();
  if (threadIdx.x < 8 && sc[threadIdx.x] > 0)
    atomicAdd(&gccnt[threadIdx.x], (float)sc[threadIdx.x]);
}

// cluster-driven new_x: wave per cluster row (nclus <= N).
__global__ void k_newx(const int* __restrict__ srcE, const int* __restrict__ src,
                       const int* __restrict__ dst, const float* __restrict__ score,
                       const int* __restrict__ nclusP, const float* __restrict__ h2,
                       float* __restrict__ new_x, int n) {
  int c = (blockIdx.x * blockDim.x + threadIdx.x) >> 6;
  int lane = threadIdx.x & 63;
  if (c >= n || c >= *nclusP) return;
  int v = srcE[c];
  float val;
  if (v >= 0) {
    int s = src[v], d = dst[v];
    val = h2[(size_t)s * 64 + lane];
    if (d != s) val += h2[(size_t)d * 64 + lane];
    val *= score[v];
  } else {
    val = h2[(size_t)(~v) * 64 + lane];
  }
  new_x[(size_t)c * 64 + lane] = val;
}

#define HBITS 21
#define HMASK ((1u << HBITS) - 1u)

// coalesce(cluster[edge_index]): hash-dedup; dups -> sentinel n; counts kept.
__global__ void k_dedup(const int* __restrict__ src, const int* __restrict__ dst,
                        const int* __restrict__ cluster, u64* __restrict__ table,
                        int* __restrict__ ns, int* __restrict__ nd,
                        int* __restrict__ cnt, int e, int n) {
  int i = blockIdx.x * blockDim.x + threadIdx.x;
  if (i >= e) return;
  int cs_ = cluster[src[i]], cd_ = cluster[dst[i]];
  u64 kk = (u64)cs_ * (u64)(n + 1) + (u64)cd_;
  u32 pos = (u32)((kk * 0x9E3779B97F4A7C15ull) >> 43) & HMASK;
  while (true) {
    u64 old = atomicCAS(&table[pos], ~0ull, kk);
    if (old == ~0ull) {
      ns[i] = cs_; nd[i] = cd_;
      atomicAdd(&cnt[cd_], 1);
      return;
    }
    if (old == kk) { ns[i] = n; nd[i] = n; return; }
    pos = (pos + 1) & HMASK;
  }
}

// JK cat + lin1 + relu + lin2 + log_softmax. single block.
__global__ void k_head(const float* __restrict__ xs_sum /*4*8*64*/,
                       const float* __restrict__ gncnt, const float* __restrict__ gccnt,
                       const float* __restrict__ l1w, const float* __restrict__ l1b,
                       const float* __restrict__ l2w, const float* __restrict__ l2b,
                       const int* __restrict__ gP, float* __restrict__ out, int C) {
  __shared__ float z[8][256];
  __shared__ float z1[8][64];
  __shared__ float z2[8][16];
  int G = *gP;
  int tid = threadIdx.x;
  int p = tid >> 6, f = tid & 63;
  for (int g = 0; g < G; ++g) {
    float c = (p < 2) ? gncnt[g] : gccnt[g];
    if (c < 1.f) c = 1.f;
    z[g][tid] = xs_sum[(p * 8 + g) * 64 + f] / c;
  }
  __syncthreads();
  for (int idx = tid; idx < G * 64; idx += blockDim.x) {
    int g = idx >> 6, o = idx & 63;
    float a = l1b[o];
    for (int k = 0; k < 256; ++k) a = fmaf(z[g][k], l1w[o * 256 + k], a);
    z1[g][o] = a > 0.f ? a : 0.f;
  }
  __syncthreads();
  for (int idx = tid; idx < G * C; idx += blockDim.x) {
    int g = idx / C, c = idx % C;
    float a = l2b[c];
    for (int k = 0; k < 64; ++k) a = fmaf(z1[g][k], l2w[c * 64 + k], a);
    z2[g][c] = a;
  }
  __syncthreads();
  if (tid < G) {
    float m = z2[tid][0];
    for (int c = 1; c < C; ++c) m = fmaxf(m, z2[tid][c]);
    float s = 0.f;
    for (int c = 0; c < C; ++c) s += expf(z2[tid][c] - m);
    float lse = m + logf(s);
    for (int c = 0; c < C; ++c) out[tid * C + c] = z2[tid][c] - lse;
  }
}

extern "C" void kernel_launch(void* const* d_in, const int* in_sizes, int n_in,
                              void* d_out, int out_size, void* d_ws, size_t ws_size,
                              hipStream_t stream) {
  const float* x       = (const float*)d_in[0];
  const int*   ei      = (const int*)d_in[1];
  const int*   batch   = (const int*)d_in[2];
  const float* w_rel1  = (const float*)d_in[3];
  const float* b_rel1  = (const float*)d_in[4];
  const float* w_root1 = (const float*)d_in[5];
  const float* w_rel2  = (const float*)d_in[6];
  const float* b_rel2  = (const float*)d_in[7];
  const float* w_root2 = (const float*)d_in[8];
  const float* w_rel3  = (const float*)d_in[9];
  const float* b_rel3  = (const float*)d_in[10];
  const float* w_root3 = (const float*)d_in[11];
  const float* w_rel4  = (const float*)d_in[12];
  const float* b_rel4  = (const float*)d_in[13];
  const float* w_root4 = (const float*)d_in[14];
  const float* pool_w  = (const float*)d_in[15];
  const float* pool_b  = (const float*)d_in[16];
  const float* lin1_w  = (const float*)d_in[17];
  const float* lin1_b  = (const float*)d_in[18];
  const float* lin2_w  = (const float*)d_in[19];
  const float* lin2_b  = (const float*)d_in[20];
  const int*   gP      = (const int*)d_in[21];
  float* out = (float*)d_out;

  const int N = in_sizes[2];
  const int E = in_sizes[1] / 2;
  const int C = in_sizes[20];
  const int* src = ei;
  const int* dst = ei + E;

  // ---- workspace layout ----
  char* w = (char*)d_ws;
  auto alloc = [&](size_t bytes) -> char* {
    char* p = w;
    w += (bytes + 255) & ~(size_t)255;
    return p;
  };
  float* r      = (float*)alloc((size_t)N * 64 * 4);
  float* agg    = (float*)alloc((size_t)(N + 1) * 64 * 4);  // also egKey/egSD + hash
  float* hA     = (float*)alloc((size_t)N * 64 * 4);        // h1 -> new_x -> h4
  float* hB     = (float*)alloc((size_t)N * 64 * 4);        // h2 -> h3
  float* score  = (float*)alloc((size_t)E * 4);             // raw -> score
  u64*   key    = (u64*)alloc((size_t)E * 8);               // ints alias: col
  int*   listA  = (int*)alloc((size_t)E * 4);               // aN -> list -> ns
  int*   listB  = (int*)alloc((size_t)E * 4);               // bN -> list -> nd
  u64*   best0  = (u64*)alloc((size_t)N * 8);
  u64*   best1  = (u64*)alloc((size_t)N * 8);
  int*   rowptr = (int*)alloc((size_t)(N + 2) * 4);
  int*   pos    = (int*)alloc((size_t)(N + 2) * 4);         // also srcE
  char* zstart = w;                                         // zeroed block
  int*   cnt       = (int*)alloc((size_t)(N + 2) * 4);
  int*   bsum      = (int*)alloc(1024);
  u32*   m_enc     = (u32*)alloc((size_t)N * 4);
  float* den       = (float*)alloc((size_t)N * 4);
  int*   dead      = (int*)alloc((size_t)N * 4);
  u8*    matched   = (u8*)alloc((size_t)E);
  int*   cluster   = (int*)alloc((size_t)N * 4);
  int*   new_batch = (int*)alloc((size_t)N * 4);
  float* small     = (float*)alloc(16384);
  size_t zbytes = (size_t)(w - zstart);
  if ((size_t)(w - (char*)d_ws) > ws_size) return;  // fail loudly

  int*   col = (int*)key;      // alias (col dead while key live, vice versa)
  float* aN  = (float*)listA;  // alias: dots dead before lists used
  float* bN  = (float*)listB;
  u64*   egKey = (u64*)agg;    // alias: agg idle during matching
  int2*  egSD  = (int2*)(egKey + E);
  int*   srcE  = pos;          // alias: pos re-filled later by 2nd scan_out

  float* xs_sum = small;                 // [4][8][64]
  float* gncnt  = small + 2048;          // [8]
  float* gccnt  = small + 2056;          // [8]
  int*   nclusP = (int*)(small + 2064);
  int*   gec    = (int*)(small + 2068);  // [8]
  int*   gbase  = (int*)(small + 2080);  // [9]
  int*   gpos   = (int*)(small + 2092);  // [8]

  const int TB = 256;
  const int gN = (N + TB - 1) / TB;
  const int gE = (E + TB - 1) / TB;
  const int gE1k = (E + 1023) / 1024;
  const int gNw = (int)(((size_t)N * 64 + TB - 1) / TB);  // wave per node
  const int nc = N + 2;
  const int nb = (nc + 1023) / 1024;

  hipMemsetAsync(zstart, 0, zbytes, stream);
  hipMemsetAsync(best0, 0xFF, (size_t)N * 8, stream);
  hipMemsetAsync(best1, 0xFF, (size_t)N * 8, stream);

  // ---- CSR for original edges ----
  k_count<<<gE, TB, 0, stream>>>(dst, cnt, E);
  k_scan_sums<<<nb, TB, 0, stream>>>(cnt, bsum, nc);
  k_scan_tops<<<1, 64, 0, stream>>>(bsum, nb);
  k_scan_out<<<nb, TB, 0, stream>>>(cnt, bsum, rowptr, pos, nc);
  k_fill<<<gE, TB, 0, stream>>>(src, dst, pos, col, E, N);

  // ---- conv1 (F=128 -> 64) + gmp xs0 ----
  k_transform<128><<<gN, TB, 0, stream>>>(x, w_rel1, nullptr, r, N);
  k_gather<<<gNw, TB, 0, stream>>>(r, rowptr, col, nullptr, agg, N);
  k_finish<128><<<gN, TB, 0, stream>>>(x, agg, rowptr, w_root1, b_rel1, nullptr, hA,
                                       nullptr, nullptr, nullptr, N);
  k_gmp<<<1024, TB, 0, stream>>>(hA, batch, gP, xs_sum + 0 * 512, gncnt, 1, N);

  // ---- conv2 (64 -> 64, fused score dots) + gmp xs1 ----
  k_transform<64><<<gN, TB, 0, stream>>>(hA, w_rel2, nullptr, r, N);
  k_gather<<<gNw, TB, 0, stream>>>(r, rowptr, col, nullptr, agg, N);
  k_finish<64><<<gN, TB, 0, stream>>>(hA, agg, rowptr, w_root2, b_rel2, nullptr, hB,
                                      pool_w, aN, bN, N);
  k_gmp<<<1024, TB, 0, stream>>>(hB, batch, gP, xs_sum + 1 * 512, nullptr, 0, N);

  // ---- edge pooling: scores ----
  k_raw2<<<gE, TB, 0, stream>>>(aN, bN, pool_b, src, dst, score, E);
  k_max<<<gE, TB, 0, stream>>>(score, dst, m_enc, E);
  k_den<<<gE, TB, 0, stream>>>(score, dst, m_enc, den, E);
  k_score<<<gE, TB, 0, stream>>>(score, dst, m_enc, den, key, E);

  // ---- partition edges by graph; per-graph greedy matching ----
  k_gcount<<<gE, TB, 0, stream>>>(src, batch, gec, E);
  k_gscan<<<1, 64, 0, stream>>>(gec, gbase, gpos);
  k_gfill<<<gE1k, 1024, 0, stream>>>(src, dst, batch, key, gP, gpos, egKey, egSD, E, N);
  k_match_wg<<<8, 1024, 0, stream>>>(egKey, egSD, gbase, gP, best0, best1,
                                     listA, listB, dead, matched, N);

  // ---- clusters, new_x, new_batch ----
  k_clinit<<<gN, TB, 0, stream>>>(new_batch, gP, N);
  k_build_m<<<gE, TB, 0, stream>>>(matched, src, dst, batch, cluster, new_batch,
                                   srcE, nclusP, gccnt, E);
  k_build_s<<<gN, TB, 0, stream>>>(dead, batch, cluster, new_batch, srcE, nclusP, gccnt, N);
  k_newx<<<gNw, TB, 0, stream>>>(srcE, src, dst, score, nclusP, hB, hA, N);

  // ---- coalesce edges + CSR for pooled edges ----
  hipMemsetAsync(agg, 0xFF, ((size_t)1 << HBITS) * 8, stream);
  hipMemsetAsync(cnt, 0, (size_t)nc * 4, stream);
  k_dedup<<<gE, TB, 0, stream>>>(src, dst, cluster, (u64*)agg, listA, listB, cnt, E, N);
  k_scan_sums<<<nb, TB, 0, stream>>>(cnt, bsum, nc);
  k_scan_tops<<<1, 64, 0, stream>>>(bsum, nb);
  k_scan_out<<<nb, TB, 0, stream>>>(cnt, bsum, rowptr, pos, nc);
  k_fill<<<gE, TB, 0, stream>>>(listA, listB, pos, col, E, N);

  // ---- conv3 (64 -> 64) + gmp xs2 ----
  k_transform<64><<<gN, TB, 0, stream>>>(hA, w_rel3, nclusP, r, N);
  k_gather<<<gNw, TB, 0, stream>>>(r, rowptr, col, nclusP, agg, N);
  k_finish<64><<<gN, TB, 0, stream>>>(hA, agg, rowptr, w_root3, b_rel3, nclusP, hB,
                                      nullptr, nullptr, nullptr, N);
  k_gmp<<<1024, TB, 0, stream>>>(hB, new_batch, gP, xs_sum + 2 * 512, nullptr, 0, N);

  // ---- conv4 (64 -> 64) + gmp xs3 ----
  k_transform<64><<<gN, TB, 0, stream>>>(hB, w_rel4, nclusP, r, N);
  k_gather<<<gNw, TB, 0, stream>>>(r, rowptr, col, nclusP, agg, N);
  k_finish<64><<<gN, TB, 0, stream>>>(hB, agg, rowptr, w_root4, b_rel4, nclusP, hA,
                                      nullptr, nullptr, nullptr, N);
  k_gmp<<<1024, TB, 0, stream>>>(hA, new_batch, gP, xs_sum + 3 * 512, nullptr, 0, N);

  // ---- head ----
  k_head<<<1, TB, 0, stream>>>(xs_sum, gncnt, gccnt, lin1_w, lin1_b, lin2_w, lin2_b, gP, out, C);
}

// Round 5
// 1936.333 us; speedup vs baseline: 1.9347x; 1.7062x over previous
//
#include <hip/hip_runtime.h>
#include <stdint.h>

typedef unsigned long long u64;
typedef unsigned int u32;
typedef unsigned char u8;

// ---------------------------------------------------------------------------
// EdgePool GNN pipeline.  N=100000, E=800000, F=128, H=64, G=8, C=10. f32.
// R1: two-stage k_gmp (was 4x1270us same-address global atomics).
// R2: dst-CSR gather (was 51M scattered atomics); factored raw scores.
// R3: per-graph workgroup matching (device-barrier fences = L2 writeback).
// R4: k_match state fully in LDS (bcur 100KB + dead 12.5KB per graph);
//     alive lists carry (key,sd) inline -> pure streaming global traffic;
//     ballot-aggregated compaction; phase-C LDS clear replaces global bnext
//     resets (117MB HBM writes gone). Fused raw+max, score+partition-fill;
//     dropped clinit/best0/best1.
// ---------------------------------------------------------------------------

static __device__ __forceinline__ u32 enc_f32(float f) {
  u32 u = __float_as_uint(f);
  return (u & 0x80000000u) ? ~u : (u | 0x80000000u);
}
static __device__ __forceinline__ float dec_f32(u32 u) {
  u32 b = (u & 0x80000000u) ? (u & 0x7fffffffu) : ~u;
  return __uint_as_float(b);
}

// out[n][64] = in[n][K] @ W[64][K]^T   (W staged in LDS, lane-uniform reads)
template <int K>
__global__ void k_transform(const float* __restrict__ x, const float* __restrict__ w,
                            const int* __restrict__ nvP, float* __restrict__ out, int n) {
  __shared__ float ws[64 * K];
  for (int i = threadIdx.x; i < 64 * K; i += blockDim.x) ws[i] = w[i];
  __syncthreads();
  int node = blockIdx.x * blockDim.x + threadIdx.x;
  if (node >= n) return;
  if (nvP && node >= *nvP) return;
  const float* xr = x + (size_t)node * K;
  float acc[64];
#pragma unroll
  for (int o = 0; o < 64; ++o) acc[o] = 0.f;
  for (int k = 0; k < K; k += 4) {
    float4 xv = *reinterpret_cast<const float4*>(xr + k);
#pragma unroll
    for (int o = 0; o < 64; ++o) {
      float4 wv = *reinterpret_cast<const float4*>(&ws[o * K + k]);
      acc[o] = fmaf(xv.x, wv.x, acc[o]);
      acc[o] = fmaf(xv.y, wv.y, acc[o]);
      acc[o] = fmaf(xv.z, wv.z, acc[o]);
      acc[o] = fmaf(xv.w, wv.w, acc[o]);
    }
  }
  float4* orow = reinterpret_cast<float4*>(out + (size_t)node * 64);
#pragma unroll
  for (int o = 0; o < 16; ++o)
    orow[o] = make_float4(acc[4 * o], acc[4 * o + 1], acc[4 * o + 2], acc[4 * o + 3]);
}

__global__ void k_count(const int* __restrict__ dst, int* __restrict__ cnt, int e) {
  int i = blockIdx.x * blockDim.x + threadIdx.x;
  if (i < e) atomicAdd(&cnt[dst[i]], 1);
}

// ---- 3-kernel exclusive scan over nc ints ----
__global__ void k_scan_sums(const int* __restrict__ in, int* __restrict__ bsum, int n) {
  __shared__ int sd[256];
  int base = blockIdx.x << 10;
  int s = 0;
  for (int j = threadIdx.x; j < 1024; j += 256) {
    int id = base + j;
    s += (id < n) ? in[id] : 0;
  }
  sd[threadIdx.x] = s;
  __syncthreads();
  for (int w = 128; w > 0; w >>= 1) {
    if (threadIdx.x < w) sd[threadIdx.x] += sd[threadIdx.x + w];
    __syncthreads();
  }
  if (threadIdx.x == 0) bsum[blockIdx.x] = sd[0];
}
__global__ void k_scan_tops(int* __restrict__ bsum, int nb) {
  if (threadIdx.x == 0 && blockIdx.x == 0) {
    int acc = 0;
    for (int i = 0; i < nb; ++i) { int v = bsum[i]; bsum[i] = acc; acc += v; }
  }
}
__global__ void k_scan_out(const int* __restrict__ in, const int* __restrict__ bsum,
                           int* __restrict__ rowptr, int* __restrict__ pos, int n) {
  __shared__ int sd[256];
  int base = blockIdx.x << 10;
  int i0 = base + threadIdx.x * 4;
  int v0 = 0, v1 = 0, v2 = 0, v3 = 0;
  if (i0 < n) v0 = in[i0];
  if (i0 + 1 < n) v1 = in[i0 + 1];
  if (i0 + 2 < n) v2 = in[i0 + 2];
  if (i0 + 3 < n) v3 = in[i0 + 3];
  sd[threadIdx.x] = v0 + v1 + v2 + v3;
  __syncthreads();
  for (int off = 1; off < 256; off <<= 1) {
    int add = (threadIdx.x >= off) ? sd[threadIdx.x - off] : 0;
    __syncthreads();
    sd[threadIdx.x] += add;
    __syncthreads();
  }
  int excl = bsum[blockIdx.x] + (threadIdx.x ? sd[threadIdx.x - 1] : 0);
  if (i0 < n) { rowptr[i0] = excl; pos[i0] = excl; }
  excl += v0;
  if (i0 + 1 < n) { rowptr[i0 + 1] = excl; pos[i0 + 1] = excl; }
  excl += v1;
  if (i0 + 2 < n) { rowptr[i0 + 2] = excl; pos[i0 + 2] = excl; }
  excl += v2;
  if (i0 + 3 < n) { rowptr[i0 + 3] = excl; pos[i0 + 3] = excl; }
}

__global__ void k_fill(const int* __restrict__ src, const int* __restrict__ dst,
                       int* __restrict__ pos, int* __restrict__ col, int e, int n) {
  int i = blockIdx.x * blockDim.x + threadIdx.x;
  if (i >= e) return;
  int d = dst[i];
  if (d >= n) return;  // sentinel (pooled duplicates)
  int j = atomicAdd(&pos[d], 1);
  col[j] = src[i];
}

// CSR gather: wave per dst node, lane = feature; coalesced 256B row loads.
__global__ void k_gather(const float* __restrict__ r, const int* __restrict__ rowptr,
                         const int* __restrict__ col, const int* __restrict__ nvP,
                         float* __restrict__ agg, int n) {
  int wv = (blockIdx.x * blockDim.x + threadIdx.x) >> 6;
  int lane = threadIdx.x & 63;
  if (wv >= n) return;
  if (nvP && wv >= *nvP) return;
  int b = rowptr[wv], e2 = rowptr[wv + 1];
  float s = 0.f;
  for (int j = b; j < e2; ++j) s += r[(size_t)col[j] * 64 + lane];
  agg[(size_t)wv * 64 + lane] = s;
}

// h = relu(agg/deg + b + xin @ w_root^T); optional fused score-dot halves.
template <int K>
__global__ void k_finish(const float* __restrict__ xin, const float* __restrict__ agg,
                         const int* __restrict__ rowptr, const float* __restrict__ w_root,
                         const float* __restrict__ bias, const int* __restrict__ nvP,
                         float* __restrict__ hout, const float* __restrict__ pw,
                         float* __restrict__ aN, float* __restrict__ bN, int n) {
  __shared__ float ws[64 * K];
  __shared__ float pws[128];
  for (int i = threadIdx.x; i < 64 * K; i += blockDim.x) ws[i] = w_root[i];
  if (pw) for (int i = threadIdx.x; i < 128; i += blockDim.x) pws[i] = pw[i];
  __syncthreads();
  int node = blockIdx.x * blockDim.x + threadIdx.x;
  if (node >= n) return;
  if (nvP && node >= *nvP) return;
  const float* xr = xin + (size_t)node * K;
  float acc[64];
#pragma unroll
  for (int o = 0; o < 64; ++o) acc[o] = bias[o];
  for (int k = 0; k < K; k += 4) {
    float4 xv = *reinterpret_cast<const float4*>(xr + k);
#pragma unroll
    for (int o = 0; o < 64; ++o) {
      float4 wv = *reinterpret_cast<const float4*>(&ws[o * K + k]);
      acc[o] = fmaf(xv.x, wv.x, acc[o]);
      acc[o] = fmaf(xv.y, wv.y, acc[o]);
      acc[o] = fmaf(xv.z, wv.z, acc[o]);
      acc[o] = fmaf(xv.w, wv.w, acc[o]);
    }
  }
  int deg = rowptr[node + 1] - rowptr[node];
  float inv = deg > 0 ? 1.f / (float)deg : 0.f;
  const float* ar = agg + (size_t)node * 64;
  float4* hr = reinterpret_cast<float4*>(hout + (size_t)node * 64);
  float d1 = 0.f, d2 = 0.f;
#pragma unroll
  for (int o4 = 0; o4 < 16; ++o4) {
    float4 a = reinterpret_cast<const float4*>(ar)[o4];
    float4 v;
    v.x = fmaf(a.x, inv, acc[4 * o4 + 0]); v.x = v.x > 0.f ? v.x : 0.f;
    v.y = fmaf(a.y, inv, acc[4 * o4 + 1]); v.y = v.y > 0.f ? v.y : 0.f;
    v.z = fmaf(a.z, inv, acc[4 * o4 + 2]); v.z = v.z > 0.f ? v.z : 0.f;
    v.w = fmaf(a.w, inv, acc[4 * o4 + 3]); v.w = v.w > 0.f ? v.w : 0.f;
    hr[o4] = v;
    if (pw) {
      d1 = fmaf(v.x, pws[4 * o4 + 0], d1); d2 = fmaf(v.x, pws[64 + 4 * o4 + 0], d2);
      d1 = fmaf(v.y, pws[4 * o4 + 1], d1); d2 = fmaf(v.y, pws[64 + 4 * o4 + 1], d2);
      d1 = fmaf(v.z, pws[4 * o4 + 2], d1); d2 = fmaf(v.z, pws[64 + 4 * o4 + 2], d2);
      d1 = fmaf(v.w, pws[4 * o4 + 3], d1); d2 = fmaf(v.w, pws[64 + 4 * o4 + 3], d2);
    }
  }
  if (pw) { aN[node] = d1; bN[node] = d2; }
}

// global mean pool, two-stage (R1); nvP bounds live rows (pooled convs).
__global__ void k_gmp(const float* __restrict__ h, const int* __restrict__ batch,
                      const int* __restrict__ gP, const int* __restrict__ nvP,
                      float* __restrict__ xs_sum, float* __restrict__ gcnt,
                      int count_nodes, int n) {
  __shared__ float sacc[8 * 64];
  __shared__ float scnt[8];
  int G = *gP;
  int nv = nvP ? *nvP : n;
  if (nv > n) nv = n;
  for (int i = threadIdx.x; i < 8 * 64; i += blockDim.x) sacc[i] = 0.f;
  if (threadIdx.x < 8) scnt[threadIdx.x] = 0.f;
  __syncthreads();
  int lane = threadIdx.x & 63, w = threadIdx.x >> 6;
  int stride = gridDim.x * 4;
  for (int node = blockIdx.x * 4 + w; node < nv; node += stride) {
    int g = batch[node];
    if (g < 0 || g >= G || g >= 8) continue;
    float v = h[(size_t)node * 64 + lane];
    atomicAdd(&sacc[g * 64 + lane], v);
    if (count_nodes && lane == 0) atomicAdd(&scnt[g], 1.f);
  }
  __syncthreads();
  int lim = (G < 8 ? G : 8) * 64;
  for (int i = threadIdx.x; i < lim; i += blockDim.x) {
    float s = sacc[i];
    if (s != 0.f) atomicAdd(&xs_sum[i], s);
  }
  if (count_nodes && threadIdx.x < 8) {
    float c = scnt[threadIdx.x];
    if (c != 0.f) atomicAdd(&gcnt[threadIdx.x], c);
  }
}

// fused: raw score + dst-grouped max
__global__ void k_rawmax(const float* __restrict__ aN, const float* __restrict__ bN,
                         const float* __restrict__ pbp, const int* __restrict__ src,
                         const int* __restrict__ dst, float* __restrict__ raw,
                         u32* __restrict__ m_enc, int e) {
  int i = blockIdx.x * blockDim.x + threadIdx.x;
  if (i >= e) return;
  int d = dst[i];
  float v = aN[src[i]] + bN[d] + pbp[0];
  raw[i] = v;
  atomicMax(&m_enc[d], enc_f32(v));
}

__global__ void k_den(const float* __restrict__ raw, const int* __restrict__ dst,
                      const u32* __restrict__ m_enc, float* __restrict__ den, int e) {
  int i = blockIdx.x * blockDim.x + threadIdx.x;
  if (i >= e) return;
  int d = dst[i];
  atomicAdd(&den[d], expf(raw[i] - dec_f32(m_enc[d])));
}

// ---- per-graph edge partition counters ----
__global__ void k_gcount(const int* __restrict__ src, const int* __restrict__ batch,
                         int* __restrict__ gec, int e) {
  __shared__ int sc[8];
  if (threadIdx.x < 8) sc[threadIdx.x] = 0;
  __syncthreads();
  int i = blockIdx.x * blockDim.x + threadIdx.x;
  if (i < e) {
    int g = batch[src[i]];
    if ((unsigned)g < 8u) atomicAdd(&sc[g], 1);
  }
  __syncthreads();
  if (threadIdx.x < 8 && sc[threadIdx.x]) atomicAdd(&gec[threadIdx.x], sc[threadIdx.x]);
}
__global__ void k_gscan(const int* __restrict__ gec, int* __restrict__ gbase,
                        int* __restrict__ gpos) {
  if (threadIdx.x == 0 && blockIdx.x == 0) {
    int acc = 0;
    for (int g = 0; g < 8; ++g) { gbase[g] = acc; gpos[g] = acc; acc += gec[g]; }
    gbase[8] = acc;
  }
}

// fused: softmax score finalize + sort key + per-graph partition fill.
// Writes round-0 alive list (keyA: {~score,idx}, sdA: local s<<16|d).
__global__ void k_scorefill(float* __restrict__ rawsc, const int* __restrict__ src,
                            const int* __restrict__ dst, const u32* __restrict__ m_enc,
                            const float* __restrict__ den, const int* __restrict__ batch,
                            const int* __restrict__ gP, int* __restrict__ gpos,
                            u64* __restrict__ keyA, u32* __restrict__ sdA, int e, int N) {
  __shared__ int scnt[8], sbase[8];
  if (threadIdx.x < 8) scnt[threadIdx.x] = 0;
  __syncthreads();
  int i = blockIdx.x * blockDim.x + threadIdx.x;
  int g = -1, rank = 0, s = 0, d = 0;
  u64 k = 0;
  if (i < e) {
    s = src[i]; d = dst[i];
    float sc = expf(rawsc[i] - dec_f32(m_enc[d])) / den[d] + 0.5f;
    rawsc[i] = sc;
    k = ((u64)(~__float_as_uint(sc)) << 32) | (u32)i;  // score desc, idx asc
    g = batch[s];
    if ((unsigned)g < 8u) rank = atomicAdd(&scnt[g], 1);
    else g = -1;
  }
  __syncthreads();
  if (threadIdx.x < 8 && scnt[threadIdx.x])
    sbase[threadIdx.x] = atomicAdd(&gpos[threadIdx.x], scnt[threadIdx.x]);
  __syncthreads();
  if (g < 0) return;
  int per = N / *gP;
  int base = g * per;
  int j = sbase[g] + rank;
  keyA[j] = k;
  sdA[j] = ((u32)(s - base) << 16) | (u32)(d - base);
}

// Per-graph exact greedy matching, one 1024-thread workgroup per graph.
// ALL random state in LDS (bcur 100KB u64 + dead 12.5KB); global traffic is
// streaming coalesced ping-pong lists carrying (key,sd) inline. Phase C
// clears bcur in LDS (R4: replaces global bnext resets = 117MB HBM writes).
#define PERMAX 12544
__global__ __launch_bounds__(1024) void k_match_wg(
    const int* __restrict__ gbase, const int* __restrict__ gP,
    u64* __restrict__ keyA, u64* __restrict__ keyB,
    u32* __restrict__ sdA, u32* __restrict__ sdB,
    int* __restrict__ dead, u8* __restrict__ matched, int N) {
  __shared__ u64 bcur[PERMAX];
  __shared__ u8 dead_s[PERMAX];
  __shared__ int lcnt;
  int G = *gP;
  int g = blockIdx.x;
  if (g >= G) return;
  int per = N / G;
  if (per > PERMAX) per = PERMAX;
  int base = g * per;
  int re = gbase[g];
  int n = gbase[g + 1] - re;
  int tid = threadIdx.x, lane = tid & 63;
  for (int i = tid; i < per; i += 1024) { bcur[i] = ~0ull; dead_s[i] = 0; }
  if (tid == 0) lcnt = 0;
  __syncthreads();
  u64* kin = keyA + re; u64* kout = keyB + re;
  u32* sin_ = sdA + re; u32* sout = sdB + re;
  for (int round = 0; n > 0 && round < 5000; ++round) {
    // Phase A: drop dead edges, claim node minima (LDS), ballot-compact
    for (int i = tid; i - lane < n; i += 1024) {
      bool inb = i < n;
      u32 sd = 0; u64 k = 0;
      if (inb) { sd = sin_[i]; k = kin[i]; }
      int s = sd >> 16, d = sd & 0xffff;
      bool alive = inb && !(dead_s[s] | dead_s[d]);
      if (alive) {
        atomicMin(&bcur[s], k);
        if (d != s) atomicMin(&bcur[d], k);
      }
      u64 m = __ballot(alive);
      if (m) {
        int lead = __ffsll((long long)m) - 1;
        int bse = 0;
        if (lane == lead) bse = atomicAdd(&lcnt, __popcll(m));
        bse = __shfl(bse, lead, 64);
        if (alive) {
          int j = bse + __popcll(m & ((1ull << lane) - 1ull));
          kout[j] = k;
          sout[j] = sd;
        }
      }
    }
    __syncthreads();
    int n2 = lcnt;
    if (n2 == 0) break;
    // Phase B: locally-dominant edges match
    for (int i = tid; i < n2; i += 1024) {
      u32 sd = sout[i];
      u64 k = kout[i];
      int s = sd >> 16, d = sd & 0xffff;
      if (bcur[s] == k && (d == s || bcur[d] == k)) {
        matched[(u32)k] = 1;
        dead_s[s] = 1;
        dead_s[d] = 1;
      }
    }
    __syncthreads();
    // Phase C: reset minima + counter for next round
    for (int i = tid; i < per; i += 1024) bcur[i] = ~0ull;
    if (tid == 0) lcnt = 0;
    __syncthreads();
    u64* tk = kin; kin = kout; kout = tk;
    u32* ts = sin_; sin_ = sout; sout = ts;
    n = n2;
  }
  __syncthreads();
  for (int i = tid; i < per; i += 1024) dead[base + i] = dead_s[i];
}

__global__ void k_build_m(const u8* __restrict__ matched, const int* __restrict__ src,
                          const int* __restrict__ dst, const int* __restrict__ batch,
                          int* __restrict__ cluster, int* __restrict__ new_batch,
                          int* __restrict__ srcE, int* __restrict__ nclus,
                          float* __restrict__ gccnt, int e) {
  __shared__ int sc[8];
  if (threadIdx.x < 8) sc[threadIdx.x] = 0;
  __syncthreads();
  int i = blockIdx.x * blockDim.x + threadIdx.x;
  if (i < e && matched[i]) {
    int c = atomicAdd(nclus, 1);
    int s = src[i], d = dst[i];
    cluster[s] = c;
    cluster[d] = c;
    srcE[c] = i;
    int g = batch[s];
    new_batch[c] = g;
    if (g >= 0 && g < 8) atomicAdd(&sc[g], 1);
  }
  __syncthreads();
  if (threadIdx.x < 8 && sc[threadIdx.x] > 0)
    atomicAdd(&gccnt[threadIdx.x], (float)sc[threadIdx.x]);
}

__global__ void k_build_s(const int* __restrict__ dead, const int* __restrict__ batch,
                          int* __restrict__ cluster, int* __restrict__ new_batch,
                          int* __restrict__ srcE, int* __restrict__ nclus,
                          float* __restrict__ gccnt, int n) {
  __shared__ int sc[8];
  if (threadIdx.x < 8) sc[threadIdx.x] = 0;
  __syncthreads();
  int i = blockIdx.x * blockDim.x + threadIdx.x;
  if (i < n && !dead[i]) {
    int c = atomicAdd(nclus, 1);
    cluster[i] = c;
    srcE[c] = ~i;  // singleton: encoded node
    int g = batch[i];
    new_batch[c] = g;
    if (g >= 0 && g < 8) atomicAdd(&sc[g], 1);
  }
  __syncthreads();
  if (threadIdx.x < 8 && sc[threadIdx.x] > 0)
    atomicAdd(&gccnt[threadIdx.x], (float)sc[threadIdx.x]);
}

// cluster-driven new_x: wave per cluster row (nclus <= N).
__global__ void k_newx(const int* __restrict__ srcE, const int* __restrict__ src,
                       const int* __restrict__ dst, const float* __restrict__ score,
                       const int* __restrict__ nclusP, const float* __restrict__ h2,
                       float* __restrict__ new_x, int n) {
  int c = (blockIdx.x * blockDim.x + threadIdx.x) >> 6;
  int lane = threadIdx.x & 63;
  if (c >= n || c >= *nclusP) return;
  int v = srcE[c];
  float val;
  if (v >= 0) {
    int s = src[v], d = dst[v];
    val = h2[(size_t)s * 64 + lane];
    if (d != s) val += h2[(size_t)d * 64 + lane];
    val *= score[v];
  } else {
    val = h2[(size_t)(~v) * 64 + lane];
  }
  new_x[(size_t)c * 64 + lane] = val;
}

#define HBITS 21
#define HMASK ((1u << HBITS) - 1u)

// coalesce(cluster[edge_index]): hash-dedup; dups -> sentinel n; counts kept.
__global__ void k_dedup(const int* __restrict__ src, const int* __restrict__ dst,
                        const int* __restrict__ cluster, u64* __restrict__ table,
                        int* __restrict__ ns, int* __restrict__ nd,
                        int* __restrict__ cnt, int e, int n) {
  int i = blockIdx.x * blockDim.x + threadIdx.x;
  if (i >= e) return;
  int cs_ = cluster[src[i]], cd_ = cluster[dst[i]];
  u64 kk = (u64)cs_ * (u64)(n + 1) + (u64)cd_;
  u32 pos = (u32)((kk * 0x9E3779B97F4A7C15ull) >> 43) & HMASK;
  while (true) {
    u64 old = atomicCAS(&table[pos], ~0ull, kk);
    if (old == ~0ull) {
      ns[i] = cs_; nd[i] = cd_;
      atomicAdd(&cnt[cd_], 1);
      return;
    }
    if (old == kk) { ns[i] = n; nd[i] = n; return; }
    pos = (pos + 1) & HMASK;
  }
}

// JK cat + lin1 + relu + lin2 + log_softmax. single block.
__global__ void k_head(const float* __restrict__ xs_sum /*4*8*64*/,
                       const float* __restrict__ gncnt, const float* __restrict__ gccnt,
                       const float* __restrict__ l1w, const float* __restrict__ l1b,
                       const float* __restrict__ l2w, const float* __restrict__ l2b,
                       const int* __restrict__ gP, float* __restrict__ out, int C) {
  __shared__ float z[8][256];
  __shared__ float z1[8][64];
  __shared__ float z2[8][16];
  int G = *gP;
  int tid = threadIdx.x;
  int p = tid >> 6, f = tid & 63;
  for (int g = 0; g < G; ++g) {
    float c = (p < 2) ? gncnt[g] : gccnt[g];
    if (c < 1.f) c = 1.f;
    z[g][tid] = xs_sum[(p * 8 + g) * 64 + f] / c;
  }
  __syncthreads();
  for (int idx = tid; idx < G * 64; idx += blockDim.x) {
    int g = idx >> 6, o = idx & 63;
    float a = l1b[o];
    for (int k = 0; k < 256; ++k) a = fmaf(z[g][k], l1w[o * 256 + k], a);
    z1[g][o] = a > 0.f ? a : 0.f;
  }
  __syncthreads();
  for (int idx = tid; idx < G * C; idx += blockDim.x) {
    int g = idx / C, c = idx % C;
    float a = l2b[c];
    for (int k = 0; k < 64; ++k) a = fmaf(z1[g][k], l2w[c * 64 + k], a);
    z2[g][c] = a;
  }
  __syncthreads();
  if (tid < G) {
    float m = z2[tid][0];
    for (int c = 1; c < C; ++c) m = fmaxf(m, z2[tid][c]);
    float s = 0.f;
    for (int c = 0; c < C; ++c) s += expf(z2[tid][c] - m);
    float lse = m + logf(s);
    for (int c = 0; c < C; ++c) out[tid * C + c] = z2[tid][c] - lse;
  }
}

extern "C" void kernel_launch(void* const* d_in, const int* in_sizes, int n_in,
                              void* d_out, int out_size, void* d_ws, size_t ws_size,
                              hipStream_t stream) {
  const float* x       = (const float*)d_in[0];
  const int*   ei      = (const int*)d_in[1];
  const int*   batch   = (const int*)d_in[2];
  const float* w_rel1  = (const float*)d_in[3];
  const float* b_rel1  = (const float*)d_in[4];
  const float* w_root1 = (const float*)d_in[5];
  const float* w_rel2  = (const float*)d_in[6];
  const float* b_rel2  = (const float*)d_in[7];
  const float* w_root2 = (const float*)d_in[8];
  const float* w_rel3  = (const float*)d_in[9];
  const float* b_rel3  = (const float*)d_in[10];
  const float* w_root3 = (const float*)d_in[11];
  const float* w_rel4  = (const float*)d_in[12];
  const float* b_rel4  = (const float*)d_in[13];
  const float* w_root4 = (const float*)d_in[14];
  const float* pool_w  = (const float*)d_in[15];
  const float* pool_b  = (const float*)d_in[16];
  const float* lin1_w  = (const float*)d_in[17];
  const float* lin1_b  = (const float*)d_in[18];
  const float* lin2_w  = (const float*)d_in[19];
  const float* lin2_b  = (const float*)d_in[20];
  const int*   gP      = (const int*)d_in[21];
  float* out = (float*)d_out;

  const int N = in_sizes[2];
  const int E = in_sizes[1] / 2;
  const int C = in_sizes[20];
  const int* src = ei;
  const int* dst = ei + E;

  // ---- workspace layout ----
  char* w = (char*)d_ws;
  auto alloc = [&](size_t bytes) -> char* {
    char* p = w;
    w += (bytes + 255) & ~(size_t)255;
    return p;
  };
  float* r      = (float*)alloc((size_t)N * 64 * 4);
  float* agg    = (float*)alloc((size_t)(N + 1) * 64 * 4);  // also match lists + hash
  float* hA     = (float*)alloc((size_t)N * 64 * 4);        // h1 -> new_x -> h4
  float* hB     = (float*)alloc((size_t)N * 64 * 4);        // h2 -> h3
  float* score  = (float*)alloc((size_t)E * 4);             // raw -> score
  u64*   key    = (u64*)alloc((size_t)E * 8);               // ints alias: col
  int*   listA  = (int*)alloc((size_t)E * 4);               // aN -> ns
  int*   listB  = (int*)alloc((size_t)E * 4);               // bN -> nd
  int*   rowptr = (int*)alloc((size_t)(N + 2) * 4);
  int*   pos    = (int*)alloc((size_t)(N + 2) * 4);         // also srcE
  char* zstart = w;                                         // zeroed block
  int*   cnt       = (int*)alloc((size_t)(N + 2) * 4);
  int*   bsum      = (int*)alloc(1024);
  u32*   m_enc     = (u32*)alloc((size_t)N * 4);
  float* den       = (float*)alloc((size_t)N * 4);
  int*   dead      = (int*)alloc((size_t)N * 4);
  u8*    matched   = (u8*)alloc((size_t)E);
  int*   cluster   = (int*)alloc((size_t)N * 4);
  int*   new_batch = (int*)alloc((size_t)N * 4);
  float* small     = (float*)alloc(16384);
  size_t zbytes = (size_t)(w - zstart);
  if ((size_t)(w - (char*)d_ws) > ws_size) return;  // fail loudly

  int*   col = (int*)key;      // alias (col unused while matching)
  float* aN  = (float*)listA;  // alias: dots dead before ns/nd used
  float* bN  = (float*)listB;
  // matching ping-pong lists alias agg (agg dead between conv2-finish and dedup)
  u64*   keyA = (u64*)agg;
  u64*   keyB = keyA + E;
  u32*   sdA  = (u32*)(keyB + E);
  u32*   sdB  = sdA + E;
  int*   srcE = pos;           // alias: pos re-filled later by 2nd scan_out

  float* xs_sum = small;                 // [4][8][64]
  float* gncnt  = small + 2048;          // [8]
  float* gccnt  = small + 2056;          // [8]
  int*   nclusP = (int*)(small + 2064);
  int*   gec    = (int*)(small + 2068);  // [8]
  int*   gbase  = (int*)(small + 2080);  // [9]
  int*   gpos   = (int*)(small + 2092);  // [8]

  const int TB = 256;
  const int gN = (N + TB - 1) / TB;
  const int gE = (E + TB - 1) / TB;
  const int gNw = (int)(((size_t)N * 64 + TB - 1) / TB);  // wave per node
  const int nc = N + 2;
  const int nb = (nc + 1023) / 1024;

  hipMemsetAsync(zstart, 0, zbytes, stream);

  // ---- CSR for original edges ----
  k_count<<<gE, TB, 0, stream>>>(dst, cnt, E);
  k_scan_sums<<<nb, TB, 0, stream>>>(cnt, bsum, nc);
  k_scan_tops<<<1, 64, 0, stream>>>(bsum, nb);
  k_scan_out<<<nb, TB, 0, stream>>>(cnt, bsum, rowptr, pos, nc);
  k_fill<<<gE, TB, 0, stream>>>(src, dst, pos, col, E, N);

  // ---- conv1 (F=128 -> 64) + gmp xs0 ----
  k_transform<128><<<gN, TB, 0, stream>>>(x, w_rel1, nullptr, r, N);
  k_gather<<<gNw, TB, 0, stream>>>(r, rowptr, col, nullptr, agg, N);
  k_finish<128><<<gN, TB, 0, stream>>>(x, agg, rowptr, w_root1, b_rel1, nullptr, hA,
                                       nullptr, nullptr, nullptr, N);
  k_gmp<<<1024, TB, 0, stream>>>(hA, batch, gP, nullptr, xs_sum + 0 * 512, gncnt, 1, N);

  // ---- conv2 (64 -> 64, fused score dots) + gmp xs1 ----
  k_transform<64><<<gN, TB, 0, stream>>>(hA, w_rel2, nullptr, r, N);
  k_gather<<<gNw, TB, 0, stream>>>(r, rowptr, col, nullptr, agg, N);
  k_finish<64><<<gN, TB, 0, stream>>>(hA, agg, rowptr, w_root2, b_rel2, nullptr, hB,
                                      pool_w, aN, bN, N);
  k_gmp<<<1024, TB, 0, stream>>>(hB, batch, gP, nullptr, xs_sum + 1 * 512, nullptr, 0, N);

  // ---- edge pooling: scores + per-graph partition ----
  k_gcount<<<gE, TB, 0, stream>>>(src, batch, gec, E);
  k_gscan<<<1, 64, 0, stream>>>(gec, gbase, gpos);
  k_rawmax<<<gE, TB, 0, stream>>>(aN, bN, pool_b, src, dst, score, m_enc, E);
  k_den<<<gE, TB, 0, stream>>>(score, dst, m_enc, den, E);
  k_scorefill<<<gE, TB, 0, stream>>>(score, src, dst, m_enc, den, batch, gP, gpos,
                                     keyA, sdA, E, N);

  // ---- greedy matching (per-graph workgroup, LDS state) ----
  k_match_wg<<<8, 1024, 0, stream>>>(gbase, gP, keyA, keyB, sdA, sdB, dead, matched, N);

  // ---- clusters, new_x, new_batch ----
  k_build_m<<<gE, TB, 0, stream>>>(matched, src, dst, batch, cluster, new_batch,
                                   srcE, nclusP, gccnt, E);
  k_build_s<<<gN, TB, 0, stream>>>(dead, batch, cluster, new_batch, srcE, nclusP, gccnt, N);
  k_newx<<<gNw, TB, 0, stream>>>(srcE, src, dst, score, nclusP, hB, hA, N);

  // ---- coalesce edges + CSR for pooled edges ----
  hipMemsetAsync(agg, 0xFF, ((size_t)1 << HBITS) * 8, stream);
  hipMemsetAsync(cnt, 0, (size_t)nc * 4, stream);
  k_dedup<<<gE, TB, 0, stream>>>(src, dst, cluster, (u64*)agg, listA, listB, cnt, E, N);
  k_scan_sums<<<nb, TB, 0, stream>>>(cnt, bsum, nc);
  k_scan_tops<<<1, 64, 0, stream>>>(bsum, nb);
  k_scan_out<<<nb, TB, 0, stream>>>(cnt, bsum, rowptr, pos, nc);
  k_fill<<<gE, TB, 0, stream>>>(listA, listB, pos, col, E, N);

  // ---- conv3 (64 -> 64) + gmp xs2 ----
  k_transform<64><<<gN, TB, 0, stream>>>(hA, w_rel3, nclusP, r, N);
  k_gather<<<gNw, TB, 0, stream>>>(r, rowptr, col, nclusP, agg, N);
  k_finish<64><<<gN, TB, 0, stream>>>(hA, agg, rowptr, w_root3, b_rel3, nclusP, hB,
                                      nullptr, nullptr, nullptr, N);
  k_gmp<<<1024, TB, 0, stream>>>(hB, new_batch, gP, nclusP, xs_sum + 2 * 512, nullptr, 0, N);

  // ---- conv4 (64 -> 64) + gmp xs3 ----
  k_transform<64><<<gN, TB, 0, stream>>>(hB, w_rel4, nclusP, r, N);
  k_gather<<<gNw, TB, 0, stream>>>(r, rowptr, col, nclusP, agg, N);
  k_finish<64><<<gN, TB, 0, stream>>>(hB, agg, rowptr, w_root4, b_rel4, nclusP, hA,
                                      nullptr, nullptr, nullptr, N);
  k_gmp<<<1024, TB, 0, stream>>>(hA, new_batch, gP, nclusP, xs_sum + 3 * 512, nullptr, 0, N);

  // ---- head ----
  k_head<<<1, TB, 0, stream>>>(xs_sum, gncnt, gccnt, lin1_w, lin1_b, lin2_w, lin2_b, gP, out, C);
}

// Round 6
// 1866.741 us; speedup vs baseline: 2.0069x; 1.0373x over previous
//
#include <hip/hip_runtime.h>
#include <stdint.h>

typedef unsigned long long u64;
typedef unsigned int u32;
typedef unsigned char u8;

// ---------------------------------------------------------------------------
// EdgePool GNN pipeline.  N=100000, E=800000, F=128, H=64, G=8, C=10. f32.
// R1: two-stage k_gmp.  R2: dst-CSR gather.  R3: per-graph WG matching.
// R4: match state in LDS, streaming inline lists, ballot compaction.
// R5: (a) XCD-affinity block swizzle in k_gather conv1/2 (per-graph 3.2MB
//     r-rows pinned to one XCD's L2); (b) epoch-tagged bcur (kills per-round
//     100KB LDS clear + 1 of 3 barriers); (c) softmax without max-sub ->
//     rawden+scorefill (2 passes, was 3) ; gcount/gscan merged into
//     count/scan_tops.
// ---------------------------------------------------------------------------

// out[n][64] = in[n][K] @ W[64][K]^T   (W staged in LDS, lane-uniform reads)
template <int K>
__global__ void k_transform(const float* __restrict__ x, const float* __restrict__ w,
                            const int* __restrict__ nvP, float* __restrict__ out, int n) {
  __shared__ float ws[64 * K];
  for (int i = threadIdx.x; i < 64 * K; i += blockDim.x) ws[i] = w[i];
  __syncthreads();
  int node = blockIdx.x * blockDim.x + threadIdx.x;
  if (node >= n) return;
  if (nvP && node >= *nvP) return;
  const float* xr = x + (size_t)node * K;
  float acc[64];
#pragma unroll
  for (int o = 0; o < 64; ++o) acc[o] = 0.f;
  for (int k = 0; k < K; k += 4) {
    float4 xv = *reinterpret_cast<const float4*>(xr + k);
#pragma unroll
    for (int o = 0; o < 64; ++o) {
      float4 wv = *reinterpret_cast<const float4*>(&ws[o * K + k]);
      acc[o] = fmaf(xv.x, wv.x, acc[o]);
      acc[o] = fmaf(xv.y, wv.y, acc[o]);
      acc[o] = fmaf(xv.z, wv.z, acc[o]);
      acc[o] = fmaf(xv.w, wv.w, acc[o]);
    }
  }
  float4* orow = reinterpret_cast<float4*>(out + (size_t)node * 64);
#pragma unroll
  for (int o = 0; o < 16; ++o)
    orow[o] = make_float4(acc[4 * o], acc[4 * o + 1], acc[4 * o + 2], acc[4 * o + 3]);
}

// fused: dst-degree count + per-graph edge count (one pass over E)
__global__ void k_count(const int* __restrict__ dst, const int* __restrict__ src,
                        const int* __restrict__ batch, int* __restrict__ cnt,
                        int* __restrict__ gec, int e) {
  __shared__ int sc[8];
  if (threadIdx.x < 8) sc[threadIdx.x] = 0;
  __syncthreads();
  int i = blockIdx.x * blockDim.x + threadIdx.x;
  if (i < e) {
    atomicAdd(&cnt[dst[i]], 1);
    int g = batch[src[i]];
    if ((unsigned)g < 8u) atomicAdd(&sc[g], 1);
  }
  __syncthreads();
  if (threadIdx.x < 8 && sc[threadIdx.x]) atomicAdd(&gec[threadIdx.x], sc[threadIdx.x]);
}

// ---- 3-kernel exclusive scan over nc ints ----
__global__ void k_scan_sums(const int* __restrict__ in, int* __restrict__ bsum, int n) {
  __shared__ int sd[256];
  int base = blockIdx.x << 10;
  int s = 0;
  for (int j = threadIdx.x; j < 1024; j += 256) {
    int id = base + j;
    s += (id < n) ? in[id] : 0;
  }
  sd[threadIdx.x] = s;
  __syncthreads();
  for (int w = 128; w > 0; w >>= 1) {
    if (threadIdx.x < w) sd[threadIdx.x] += sd[threadIdx.x + w];
    __syncthreads();
  }
  if (threadIdx.x == 0) bsum[blockIdx.x] = sd[0];
}
// serial block-top scan; optionally also per-graph base/pos scan
__global__ void k_scan_tops(int* __restrict__ bsum, int nb, const int* __restrict__ gec,
                            int* __restrict__ gbase, int* __restrict__ gpos) {
  if (threadIdx.x == 0 && blockIdx.x == 0) {
    int acc = 0;
    for (int i = 0; i < nb; ++i) { int v = bsum[i]; bsum[i] = acc; acc += v; }
    if (gec) {
      int a2 = 0;
      for (int g = 0; g < 8; ++g) { gbase[g] = a2; gpos[g] = a2; a2 += gec[g]; }
      gbase[8] = a2;
    }
  }
}
__global__ void k_scan_out(const int* __restrict__ in, const int* __restrict__ bsum,
                           int* __restrict__ rowptr, int* __restrict__ pos, int n) {
  __shared__ int sd[256];
  int base = blockIdx.x << 10;
  int i0 = base + threadIdx.x * 4;
  int v0 = 0, v1 = 0, v2 = 0, v3 = 0;
  if (i0 < n) v0 = in[i0];
  if (i0 + 1 < n) v1 = in[i0 + 1];
  if (i0 + 2 < n) v2 = in[i0 + 2];
  if (i0 + 3 < n) v3 = in[i0 + 3];
  sd[threadIdx.x] = v0 + v1 + v2 + v3;
  __syncthreads();
  for (int off = 1; off < 256; off <<= 1) {
    int add = (threadIdx.x >= off) ? sd[threadIdx.x - off] : 0;
    __syncthreads();
    sd[threadIdx.x] += add;
    __syncthreads();
  }
  int excl = bsum[blockIdx.x] + (threadIdx.x ? sd[threadIdx.x - 1] : 0);
  if (i0 < n) { rowptr[i0] = excl; pos[i0] = excl; }
  excl += v0;
  if (i0 + 1 < n) { rowptr[i0 + 1] = excl; pos[i0 + 1] = excl; }
  excl += v1;
  if (i0 + 2 < n) { rowptr[i0 + 2] = excl; pos[i0 + 2] = excl; }
  excl += v2;
  if (i0 + 3 < n) { rowptr[i0 + 3] = excl; pos[i0 + 3] = excl; }
}

__global__ void k_fill(const int* __restrict__ src, const int* __restrict__ dst,
                       int* __restrict__ pos, int* __restrict__ col, int e, int n) {
  int i = blockIdx.x * blockDim.x + threadIdx.x;
  if (i >= e) return;
  int d = dst[i];
  if (d >= n) return;  // sentinel (pooled duplicates)
  int j = atomicAdd(&pos[d], 1);
  col[j] = src[i];
}

// CSR gather: wave per dst node, lane = feature; coalesced 256B row loads.
// swz: XCD-affinity permutation — chunk (blockIdx&7) covers one contiguous
// eighth of the nodes (= one graph at G=8), pinning its 3.2MB r-rows to one
// XCD's L2. Performance heuristic only; correct for any dispatch mapping.
__global__ void k_gather(const float* __restrict__ r, const int* __restrict__ rowptr,
                         const int* __restrict__ col, const int* __restrict__ nvP,
                         float* __restrict__ agg, int n, int swz) {
  int b = blockIdx.x;
  if (swz) { int chunk = gridDim.x >> 3; b = (b & 7) * chunk + (b >> 3); }
  int wv = (b * blockDim.x + threadIdx.x) >> 6;
  int lane = threadIdx.x & 63;
  if (wv >= n) return;
  if (nvP && wv >= *nvP) return;
  int bg = rowptr[wv], e2 = rowptr[wv + 1];
  float s = 0.f;
  for (int j = bg; j < e2; ++j) s += r[(size_t)col[j] * 64 + lane];
  agg[(size_t)wv * 64 + lane] = s;
}

// h = relu(agg/deg + b + xin @ w_root^T); optional fused score-dot halves.
template <int K>
__global__ void k_finish(const float* __restrict__ xin, const float* __restrict__ agg,
                         const int* __restrict__ rowptr, const float* __restrict__ w_root,
                         const float* __restrict__ bias, const int* __restrict__ nvP,
                         float* __restrict__ hout, const float* __restrict__ pw,
                         float* __restrict__ aN, float* __restrict__ bN, int n) {
  __shared__ float ws[64 * K];
  __shared__ float pws[128];
  for (int i = threadIdx.x; i < 64 * K; i += blockDim.x) ws[i] = w_root[i];
  if (pw) for (int i = threadIdx.x; i < 128; i += blockDim.x) pws[i] = pw[i];
  __syncthreads();
  int node = blockIdx.x * blockDim.x + threadIdx.x;
  if (node >= n) return;
  if (nvP && node >= *nvP) return;
  const float* xr = xin + (size_t)node * K;
  float acc[64];
#pragma unroll
  for (int o = 0; o < 64; ++o) acc[o] = bias[o];
  for (int k = 0; k < K; k += 4) {
    float4 xv = *reinterpret_cast<const float4*>(xr + k);
#pragma unroll
    for (int o = 0; o < 64; ++o) {
      float4 wv = *reinterpret_cast<const float4*>(&ws[o * K + k]);
      acc[o] = fmaf(xv.x, wv.x, acc[o]);
      acc[o] = fmaf(xv.y, wv.y, acc[o]);
      acc[o] = fmaf(xv.z, wv.z, acc[o]);
      acc[o] = fmaf(xv.w, wv.w, acc[o]);
    }
  }
  int deg = rowptr[node + 1] - rowptr[node];
  float inv = deg > 0 ? 1.f / (float)deg : 0.f;
  const float* ar = agg + (size_t)node * 64;
  float4* hr = reinterpret_cast<float4*>(hout + (size_t)node * 64);
  float d1 = 0.f, d2 = 0.f;
#pragma unroll
  for (int o4 = 0; o4 < 16; ++o4) {
    float4 a = reinterpret_cast<const float4*>(ar)[o4];
    float4 v;
    v.x = fmaf(a.x, inv, acc[4 * o4 + 0]); v.x = v.x > 0.f ? v.x : 0.f;
    v.y = fmaf(a.y, inv, acc[4 * o4 + 1]); v.y = v.y > 0.f ? v.y : 0.f;
    v.z = fmaf(a.z, inv, acc[4 * o4 + 2]); v.z = v.z > 0.f ? v.z : 0.f;
    v.w = fmaf(a.w, inv, acc[4 * o4 + 3]); v.w = v.w > 0.f ? v.w : 0.f;
    hr[o4] = v;
    if (pw) {
      d1 = fmaf(v.x, pws[4 * o4 + 0], d1); d2 = fmaf(v.x, pws[64 + 4 * o4 + 0], d2);
      d1 = fmaf(v.y, pws[4 * o4 + 1], d1); d2 = fmaf(v.y, pws[64 + 4 * o4 + 1], d2);
      d1 = fmaf(v.z, pws[4 * o4 + 2], d1); d2 = fmaf(v.z, pws[64 + 4 * o4 + 2], d2);
      d1 = fmaf(v.w, pws[4 * o4 + 3], d1); d2 = fmaf(v.w, pws[64 + 4 * o4 + 3], d2);
    }
  }
  if (pw) { aN[node] = d1; bN[node] = d2; }
}

// global mean pool, two-stage (R1); nvP bounds live rows (pooled convs).
__global__ void k_gmp(const float* __restrict__ h, const int* __restrict__ batch,
                      const int* __restrict__ gP, const int* __restrict__ nvP,
                      float* __restrict__ xs_sum, float* __restrict__ gcnt,
                      int count_nodes, int n) {
  __shared__ float sacc[8 * 64];
  __shared__ float scnt[8];
  int G = *gP;
  int nv = nvP ? *nvP : n;
  if (nv > n) nv = n;
  for (int i = threadIdx.x; i < 8 * 64; i += blockDim.x) sacc[i] = 0.f;
  if (threadIdx.x < 8) scnt[threadIdx.x] = 0.f;
  __syncthreads();
  int lane = threadIdx.x & 63, w = threadIdx.x >> 6;
  int stride = gridDim.x * 4;
  for (int node = blockIdx.x * 4 + w; node < nv; node += stride) {
    int g = batch[node];
    if (g < 0 || g >= G || g >= 8) continue;
    float v = h[(size_t)node * 64 + lane];
    atomicAdd(&sacc[g * 64 + lane], v);
    if (count_nodes && lane == 0) atomicAdd(&scnt[g], 1.f);
  }
  __syncthreads();
  int lim = (G < 8 ? G : 8) * 64;
  for (int i = threadIdx.x; i < lim; i += blockDim.x) {
    float s = sacc[i];
    if (s != 0.f) atomicAdd(&xs_sum[i], s);
  }
  if (count_nodes && threadIdx.x < 8) {
    float c = scnt[threadIdx.x];
    if (c != 0.f) atomicAdd(&gcnt[threadIdx.x], c);
  }
}

// fused: raw score + exp + dst-grouped denominator (no max-sub: raw is O(10),
// expf safe; score ratio matches reference to ~1 ulp)
__global__ void k_rawden(const float* __restrict__ aN, const float* __restrict__ bN,
                         const float* __restrict__ pbp, const int* __restrict__ src,
                         const int* __restrict__ dst, float* __restrict__ exs,
                         float* __restrict__ den, int e) {
  int i = blockIdx.x * blockDim.x + threadIdx.x;
  if (i >= e) return;
  int d = dst[i];
  float ex = expf(aN[src[i]] + bN[d] + pbp[0]);
  exs[i] = ex;
  atomicAdd(&den[d], ex);
}

// fused: score finalize + 52-bit sort key + per-graph partition fill.
// key52 = (~score_bits << 20) | edge_idx (E < 2^20): score desc, idx asc.
__global__ void k_scorefill(float* __restrict__ exsc, const int* __restrict__ src,
                            const int* __restrict__ dst, const float* __restrict__ den,
                            const int* __restrict__ batch, const int* __restrict__ gP,
                            int* __restrict__ gpos, u64* __restrict__ keyA,
                            u32* __restrict__ sdA, int e, int N) {
  __shared__ int scnt[8], sbase[8];
  if (threadIdx.x < 8) scnt[threadIdx.x] = 0;
  __syncthreads();
  int i = blockIdx.x * blockDim.x + threadIdx.x;
  int g = -1, rank = 0, s = 0, d = 0;
  u64 k = 0;
  if (i < e) {
    s = src[i]; d = dst[i];
    float sc = exsc[i] / den[d] + 0.5f;
    exsc[i] = sc;
    k = ((u64)(u32)(~__float_as_uint(sc)) << 20) | (u32)i;
    g = batch[s];
    if ((unsigned)g < 8u) rank = atomicAdd(&scnt[g], 1);
    else g = -1;
  }
  __syncthreads();
  if (threadIdx.x < 8 && scnt[threadIdx.x])
    sbase[threadIdx.x] = atomicAdd(&gpos[threadIdx.x], scnt[threadIdx.x]);
  __syncthreads();
  if (g < 0) return;
  int per = N / *gP;
  int base = g * per;
  int j = sbase[g] + rank;
  keyA[j] = k;
  sdA[j] = ((u32)(s - base) << 16) | (u32)(d - base);
}

// Per-graph exact greedy matching, one 1024-thread workgroup per graph.
// R5: epoch-tagged bcur values ((4095-round)<<52 | key52) — newer rounds
// always win atomicMin, so no per-round clear and only 2 barriers/round.
#define PERMAX 12544
__global__ __launch_bounds__(1024) void k_match_wg(
    const int* __restrict__ gbase, const int* __restrict__ gP,
    u64* __restrict__ keyA, u64* __restrict__ keyB,
    u32* __restrict__ sdA, u32* __restrict__ sdB,
    int* __restrict__ dead, u8* __restrict__ matched, int N) {
  __shared__ u64 bcur[PERMAX];
  __shared__ u8 dead_s[PERMAX];
  __shared__ int lcnt;
  int G = *gP;
  int g = blockIdx.x;
  if (g >= G) return;
  int per = N / G;
  if (per > PERMAX) per = PERMAX;
  int base = g * per;
  int re = gbase[g];
  int n = gbase[g + 1] - re;
  int tid = threadIdx.x, lane = tid & 63;
  for (int i = tid; i < per; i += 1024) { bcur[i] = ~0ull; dead_s[i] = 0; }
  if (tid == 0) lcnt = 0;
  __syncthreads();
  u64* kin = keyA + re; u64* kout = keyB + re;
  u32* sin_ = sdA + re; u32* sout = sdB + re;
  for (int round = 0; n > 0 && round < 4000; ++round) {
    u64 etag = (u64)(4095 - round) << 52;
    // Phase A: drop dead edges, claim node minima (LDS), ballot-compact
    for (int i = tid; i - lane < n; i += 1024) {
      bool inb = i < n;
      u32 sd = 0; u64 k = 0;
      if (inb) { sd = sin_[i]; k = kin[i]; }
      int s = sd >> 16, d = sd & 0xffff;
      bool alive = inb && !(dead_s[s] | dead_s[d]);
      if (alive) {
        u64 val = etag | k;
        atomicMin(&bcur[s], val);
        if (d != s) atomicMin(&bcur[d], val);
      }
      u64 m = __ballot(alive);
      if (m) {
        int lead = __ffsll((long long)m) - 1;
        int bse = 0;
        if (lane == lead) bse = atomicAdd(&lcnt, __popcll(m));
        bse = __shfl(bse, lead, 64);
        if (alive) {
          int j = bse + __popcll(m & ((1ull << lane) - 1ull));
          kout[j] = k;
          sout[j] = sd;
        }
      }
    }
    __syncthreads();
    int n2 = lcnt;
    if (n2 == 0) break;
    // Phase B: locally-dominant edges match
    for (int i = tid; i < n2; i += 1024) {
      u32 sd = sout[i];
      u64 k = kout[i];
      int s = sd >> 16, d = sd & 0xffff;
      u64 val = etag | k;
      if (bcur[s] == val && (d == s || bcur[d] == val)) {
        matched[(u32)(k & 0xFFFFF)] = 1;
        dead_s[s] = 1;
        dead_s[d] = 1;
      }
    }
    if (tid == 0) lcnt = 0;
    __syncthreads();
    u64* tk = kin; kin = kout; kout = tk;
    u32* ts = sin_; sin_ = sout; sout = ts;
    n = n2;
  }
  __syncthreads();
  for (int i = tid; i < per; i += 1024) dead[base + i] = dead_s[i];
}

__global__ void k_build_m(const u8* __restrict__ matched, const int* __restrict__ src,
                          const int* __restrict__ dst, const int* __restrict__ batch,
                          int* __restrict__ cluster, int* __restrict__ new_batch,
                          int* __restrict__ srcE, int* __restrict__ nclus,
                          float* __restrict__ gccnt, int e) {
  __shared__ int sc[8];
  if (threadIdx.x < 8) sc[threadIdx.x] = 0;
  __syncthreads();
  int i = blockIdx.x * blockDim.x + threadIdx.x;
  if (i < e && matched[i]) {
    int c = atomicAdd(nclus, 1);
    int s = src[i], d = dst[i];
    cluster[s] = c;
    cluster[d] = c;
    srcE[c] = i;
    int g = batch[s];
    new_batch[c] = g;
    if (g >= 0 && g < 8) atomicAdd(&sc[g], 1);
  }
  __syncthreads();
  if (threadIdx.x < 8 && sc[threadIdx.x] > 0)
    atomicAdd(&gccnt[threadIdx.x], (float)sc[threadIdx.x]);
}

__global__ void k_build_s(const int* __restrict__ dead, const int* __restrict__ batch,
                          int* __restrict__ cluster, int* __restrict__ new_batch,
                          int* __restrict__ srcE, int* __restrict__ nclus,
                          float* __restrict__ gccnt, int n) {
  __shared__ int sc[8];
  if (threadIdx.x < 8) sc[threadIdx.x] = 0;
  __syncthreads();
  int i = blockIdx.x * blockDim.x + threadIdx.x;
  if (i < n && !dead[i]) {
    int c = atomicAdd(nclus, 1);
    cluster[i] = c;
    srcE[c] = ~i;  // singleton: encoded node
    int g = batch[i];
    new_batch[c] = g;
    if (g >= 0 && g < 8) atomicAdd(&sc[g], 1);
  }
  __syncthreads();
  if (threadIdx.x < 8 && sc[threadIdx.x] > 0)
    atomicAdd(&gccnt[threadIdx.x], (float)sc[threadIdx.x]);
}

// cluster-driven new_x: wave per cluster row (nclus <= N).
__global__ void k_newx(const int* __restrict__ srcE, const int* __restrict__ src,
                       const int* __restrict__ dst, const float* __restrict__ score,
                       const int* __restrict__ nclusP, const float* __restrict__ h2,
                       float* __restrict__ new_x, int n) {
  int c = (blockIdx.x * blockDim.x + threadIdx.x) >> 6;
  int lane = threadIdx.x & 63;
  if (c >= n || c >= *nclusP) return;
  int v = srcE[c];
  float val;
  if (v >= 0) {
    int s = src[v], d = dst[v];
    val = h2[(size_t)s * 64 + lane];
    if (d != s) val += h2[(size_t)d * 64 + lane];
    val *= score[v];
  } else {
    val = h2[(size_t)(~v) * 64 + lane];
  }
  new_x[(size_t)c * 64 + lane] = val;
}

#define HBITS 21
#define HMASK ((1u << HBITS) - 1u)

// coalesce(cluster[edge_index]): hash-dedup; dups -> sentinel n; counts kept.
__global__ void k_dedup(const int* __restrict__ src, const int* __restrict__ dst,
                        const int* __restrict__ cluster, u64* __restrict__ table,
                        int* __restrict__ ns, int* __restrict__ nd,
                        int* __restrict__ cnt, int e, int n) {
  int i = blockIdx.x * blockDim.x + threadIdx.x;
  if (i >= e) return;
  int cs_ = cluster[src[i]], cd_ = cluster[dst[i]];
  u64 kk = (u64)cs_ * (u64)(n + 1) + (u64)cd_;
  u32 pos = (u32)((kk * 0x9E3779B97F4A7C15ull) >> 43) & HMASK;
  while (true) {
    u64 old = atomicCAS(&table[pos], ~0ull, kk);
    if (old == ~0ull) {
      ns[i] = cs_; nd[i] = cd_;
      atomicAdd(&cnt[cd_], 1);
      return;
    }
    if (old == kk) { ns[i] = n; nd[i] = n; return; }
    pos = (pos + 1) & HMASK;
  }
}

// JK cat + lin1 + relu + lin2 + log_softmax. single block.
__global__ void k_head(const float* __restrict__ xs_sum /*4*8*64*/,
                       const float* __restrict__ gncnt, const float* __restrict__ gccnt,
                       const float* __restrict__ l1w, const float* __restrict__ l1b,
                       const float* __restrict__ l2w, const float* __restrict__ l2b,
                       const int* __restrict__ gP, float* __restrict__ out, int C) {
  __shared__ float z[8][256];
  __shared__ float z1[8][64];
  __shared__ float z2[8][16];
  int G = *gP;
  int tid = threadIdx.x;
  int p = tid >> 6, f = tid & 63;
  for (int g = 0; g < G; ++g) {
    float c = (p < 2) ? gncnt[g] : gccnt[g];
    if (c < 1.f) c = 1.f;
    z[g][tid] = xs_sum[(p * 8 + g) * 64 + f] / c;
  }
  __syncthreads();
  for (int idx = tid; idx < G * 64; idx += blockDim.x) {
    int g = idx >> 6, o = idx & 63;
    float a = l1b[o];
    for (int k = 0; k < 256; ++k) a = fmaf(z[g][k], l1w[o * 256 + k], a);
    z1[g][o] = a > 0.f ? a : 0.f;
  }
  __syncthreads();
  for (int idx = tid; idx < G * C; idx += blockDim.x) {
    int g = idx / C, c = idx % C;
    float a = l2b[c];
    for (int k = 0; k < 64; ++k) a = fmaf(z1[g][k], l2w[c * 64 + k], a);
    z2[g][c] = a;
  }
  __syncthreads();
  if (tid < G) {
    float m = z2[tid][0];
    for (int c = 1; c < C; ++c) m = fmaxf(m, z2[tid][c]);
    float s = 0.f;
    for (int c = 0; c < C; ++c) s += expf(z2[tid][c] - m);
    float lse = m + logf(s);
    for (int c = 0; c < C; ++c) out[tid * C + c] = z2[tid][c] - lse;
  }
}

extern "C" void kernel_launch(void* const* d_in, const int* in_sizes, int n_in,
                              void* d_out, int out_size, void* d_ws, size_t ws_size,
                              hipStream_t stream) {
  const float* x       = (const float*)d_in[0];
  const int*   ei      = (const int*)d_in[1];
  const int*   batch   = (const int*)d_in[2];
  const float* w_rel1  = (const float*)d_in[3];
  const float* b_rel1  = (const float*)d_in[4];
  const float* w_root1 = (const float*)d_in[5];
  const float* w_rel2  = (const float*)d_in[6];
  const float* b_rel2  = (const float*)d_in[7];
  const float* w_root2 = (const float*)d_in[8];
  const float* w_rel3  = (const float*)d_in[9];
  const float* b_rel3  = (const float*)d_in[10];
  const float* w_root3 = (const float*)d_in[11];
  const float* w_rel4  = (const float*)d_in[12];
  const float* b_rel4  = (const float*)d_in[13];
  const float* w_root4 = (const float*)d_in[14];
  const float* pool_w  = (const float*)d_in[15];
  const float* pool_b  = (const float*)d_in[16];
  const float* lin1_w  = (const float*)d_in[17];
  const float* lin1_b  = (const float*)d_in[18];
  const float* lin2_w  = (const float*)d_in[19];
  const float* lin2_b  = (const float*)d_in[20];
  const int*   gP      = (const int*)d_in[21];
  float* out = (float*)d_out;

  const int N = in_sizes[2];
  const int E = in_sizes[1] / 2;
  const int C = in_sizes[20];
  const int* src = ei;
  const int* dst = ei + E;

  // ---- workspace layout ----
  char* w = (char*)d_ws;
  auto alloc = [&](size_t bytes) -> char* {
    char* p = w;
    w += (bytes + 255) & ~(size_t)255;
    return p;
  };
  float* r      = (float*)alloc((size_t)N * 64 * 4);
  float* agg    = (float*)alloc((size_t)(N + 1) * 64 * 4);  // also match lists + hash
  float* hA     = (float*)alloc((size_t)N * 64 * 4);        // h1 -> new_x -> h4
  float* hB     = (float*)alloc((size_t)N * 64 * 4);        // h2 -> h3
  float* score  = (float*)alloc((size_t)E * 4);             // ex -> score
  u64*   key    = (u64*)alloc((size_t)E * 8);               // ints alias: col
  int*   listA  = (int*)alloc((size_t)E * 4);               // aN -> ns
  int*   listB  = (int*)alloc((size_t)E * 4);               // bN -> nd
  int*   rowptr = (int*)alloc((size_t)(N + 2) * 4);
  int*   pos    = (int*)alloc((size_t)(N + 2) * 4);         // also srcE
  char* zstart = w;                                         // zeroed block
  int*   cnt       = (int*)alloc((size_t)(N + 2) * 4);
  int*   bsum      = (int*)alloc(1024);
  float* den       = (float*)alloc((size_t)N * 4);
  int*   dead      = (int*)alloc((size_t)N * 4);
  u8*    matched   = (u8*)alloc((size_t)E);
  int*   cluster   = (int*)alloc((size_t)N * 4);
  int*   new_batch = (int*)alloc((size_t)N * 4);
  float* small     = (float*)alloc(16384);
  size_t zbytes = (size_t)(w - zstart);
  if ((size_t)(w - (char*)d_ws) > ws_size) return;  // fail loudly

  int*   col = (int*)key;      // alias (col unused while matching)
  float* aN  = (float*)listA;  // alias: dots dead before ns/nd used
  float* bN  = (float*)listB;
  // matching ping-pong lists alias agg (agg dead between conv2-finish and dedup)
  u64*   keyA = (u64*)agg;
  u64*   keyB = keyA + E;
  u32*   sdA  = (u32*)(keyB + E);
  u32*   sdB  = sdA + E;
  int*   srcE = pos;           // alias: pos re-filled later by 2nd scan_out

  float* xs_sum = small;                 // [4][8][64]
  float* gncnt  = small + 2048;          // [8]
  float* gccnt  = small + 2056;          // [8]
  int*   nclusP = (int*)(small + 2064);
  int*   gec    = (int*)(small + 2068);  // [8]
  int*   gbase  = (int*)(small + 2080);  // [9]
  int*   gpos   = (int*)(small + 2092);  // [8]

  const int TB = 256;
  const int gN = (N + TB - 1) / TB;
  const int gE = (E + TB - 1) / TB;
  const int gNw = (int)(((size_t)N * 64 + TB - 1) / TB);  // wave per node
  const int swz = (gNw % 8 == 0) ? 1 : 0;                 // XCD-affinity permutation
  const int nc = N + 2;
  const int nb = (nc + 1023) / 1024;

  hipMemsetAsync(zstart, 0, zbytes, stream);

  // ---- CSR for original edges (+ per-graph edge counts) ----
  k_count<<<gE, TB, 0, stream>>>(dst, src, batch, cnt, gec, E);
  k_scan_sums<<<nb, TB, 0, stream>>>(cnt, bsum, nc);
  k_scan_tops<<<1, 64, 0, stream>>>(bsum, nb, gec, gbase, gpos);
  k_scan_out<<<nb, TB, 0, stream>>>(cnt, bsum, rowptr, pos, nc);
  k_fill<<<gE, TB, 0, stream>>>(src, dst, pos, col, E, N);

  // ---- conv1 (F=128 -> 64) + gmp xs0 ----
  k_transform<128><<<gN, TB, 0, stream>>>(x, w_rel1, nullptr, r, N);
  k_gather<<<gNw, TB, 0, stream>>>(r, rowptr, col, nullptr, agg, N, swz);
  k_finish<128><<<gN, TB, 0, stream>>>(x, agg, rowptr, w_root1, b_rel1, nullptr, hA,
                                       nullptr, nullptr, nullptr, N);
  k_gmp<<<1024, TB, 0, stream>>>(hA, batch, gP, nullptr, xs_sum + 0 * 512, gncnt, 1, N);

  // ---- conv2 (64 -> 64, fused score dots) + gmp xs1 ----
  k_transform<64><<<gN, TB, 0, stream>>>(hA, w_rel2, nullptr, r, N);
  k_gather<<<gNw, TB, 0, stream>>>(r, rowptr, col, nullptr, agg, N, swz);
  k_finish<64><<<gN, TB, 0, stream>>>(hA, agg, rowptr, w_root2, b_rel2, nullptr, hB,
                                      pool_w, aN, bN, N);
  k_gmp<<<1024, TB, 0, stream>>>(hB, batch, gP, nullptr, xs_sum + 1 * 512, nullptr, 0, N);

  // ---- edge pooling: scores + per-graph partition ----
  k_rawden<<<gE, TB, 0, stream>>>(aN, bN, pool_b, src, dst, score, den, E);
  k_scorefill<<<gE, TB, 0, stream>>>(score, src, dst, den, batch, gP, gpos,
                                     keyA, sdA, E, N);

  // ---- greedy matching (per-graph workgroup, LDS state, epoch-tagged) ----
  k_match_wg<<<8, 1024, 0, stream>>>(gbase, gP, keyA, keyB, sdA, sdB, dead, matched, N);

  // ---- clusters, new_x, new_batch ----
  k_build_m<<<gE, TB, 0, stream>>>(matched, src, dst, batch, cluster, new_batch,
                                   srcE, nclusP, gccnt, E);
  k_build_s<<<gN, TB, 0, stream>>>(dead, batch, cluster, new_batch, srcE, nclusP, gccnt, N);
  k_newx<<<gNw, TB, 0, stream>>>(srcE, src, dst, score, nclusP, hB, hA, N);

  // ---- coalesce edges + CSR for pooled edges ----
  hipMemsetAsync(agg, 0xFF, ((size_t)1 << HBITS) * 8, stream);
  hipMemsetAsync(cnt, 0, (size_t)nc * 4, stream);
  k_dedup<<<gE, TB, 0, stream>>>(src, dst, cluster, (u64*)agg, listA, listB, cnt, E, N);
  k_scan_sums<<<nb, TB, 0, stream>>>(cnt, bsum, nc);
  k_scan_tops<<<1, 64, 0, stream>>>(bsum, nb, nullptr, nullptr, nullptr);
  k_scan_out<<<nb, TB, 0, stream>>>(cnt, bsum, rowptr, pos, nc);
  k_fill<<<gE, TB, 0, stream>>>(listA, listB, pos, col, E, N);

  // ---- conv3 (64 -> 64) + gmp xs2 ----
  k_transform<64><<<gN, TB, 0, stream>>>(hA, w_rel3, nclusP, r, N);
  k_gather<<<gNw, TB, 0, stream>>>(r, rowptr, col, nclusP, agg, N, 0);
  k_finish<64><<<gN, TB, 0, stream>>>(hA, agg, rowptr, w_root3, b_rel3, nclusP, hB,
                                      nullptr, nullptr, nullptr, N);
  k_gmp<<<1024, TB, 0, stream>>>(hB, new_batch, gP, nclusP, xs_sum + 2 * 512, nullptr, 0, N);

  // ---- conv4 (64 -> 64) + gmp xs3 ----
  k_transform<64><<<gN, TB, 0, stream>>>(hB, w_rel4, nclusP, r, N);
  k_gather<<<gNw, TB, 0, stream>>>(r, rowptr, col, nclusP, agg, N, 0);
  k_finish<64><<<gN, TB, 0, stream>>>(hB, agg, rowptr, w_root4, b_rel4, nclusP, hA,
                                      nullptr, nullptr, nullptr, N);
  k_gmp<<<1024, TB, 0, stream>>>(hA, new_batch, gP, nclusP, xs_sum + 3 * 512, nullptr, 0, N);

  // ---- head ----
  k_head<<<1, TB, 0, stream>>>(xs_sum, gncnt, gccnt, lin1_w, lin1_b, lin2_w, lin2_b, gP, out, C);
}